// Round 9
// baseline (742.165 us; speedup 1.0000x reference)
//
#include <hip/hip_runtime.h>
#include <hip/hip_bf16.h>
#include <hip/hip_cooperative_groups.h>
#include <string.h>

namespace cg = cooperative_groups;

#define BB 8
#define NC 4096
#define NTT 4096
#define NNODE 1024
#define NEDGE 16384
#define LDE 4128   // embT row-dim padded (+64B) to break 8KB power-of-2 stride
#define LDL 1056   // latT row-dim padded (+64B) to break 2KB power-of-2 stride

typedef __hip_bfloat16 bf16;
typedef unsigned short u16;
typedef __attribute__((ext_vector_type(8))) short short8;
typedef __attribute__((ext_vector_type(4))) float f32x4;

__device__ __forceinline__ float b2f(bf16 x) { return __bfloat162float(x); }
__device__ __forceinline__ float bs2f(short s) { return __uint_as_float(((unsigned)(unsigned short)s) << 16); }

template <typename T> struct Cvt;
template <> struct Cvt<float> { static __device__ __forceinline__ float to(float v) { return v; } };
template <> struct Cvt<bf16>  { static __device__ __forceinline__ bf16  to(float v) { return __float2bfloat16(v); } };

__device__ __forceinline__ unsigned short f2bs(float x) {
    unsigned u = __float_as_uint(x);
    return (unsigned short)((u + 0x7FFFu + ((u >> 16) & 1u)) >> 16);
}

__device__ __forceinline__ short8 ld_frag(const bf16* g) {
    union { uint4 u4; short8 s8; } cv;
    cv.u4 = *(const uint4*)g;
    return cv.s8;
}
__device__ __forceinline__ short8 ld_frag(const float* g) {
    float4 f0 = *(const float4*)g;
    float4 f1 = *(const float4*)(g + 4);
    short8 r;
    r[0] = (short)f2bs(f0.x); r[1] = (short)f2bs(f0.y);
    r[2] = (short)f2bs(f0.z); r[3] = (short)f2bs(f0.w);
    r[4] = (short)f2bs(f1.x); r[5] = (short)f2bs(f1.y);
    r[6] = (short)f2bs(f1.z); r[7] = (short)f2bs(f1.w);
    return r;
}

// ---------------------------------------------------------------------------
__global__ void detect_k(const u16* __restrict__ posu, int* __restrict__ flag) {
    __shared__ int cnt;
    if (threadIdx.x == 0) cnt = 0;
    __syncthreads();
    int wild = 0;
    for (int i = threadIdx.x; i < 1024; i += 256) {
        u16 u = posu[2 * i];
        int ex = (u >> 7) & 0xFF;
        if (ex == 0 || ex == 0xFF || ex > 137 || ex < 107) wild++;
    }
    atomicAdd(&cnt, wild);
    __syncthreads();
    if (threadIdx.x == 0) *flag = (cnt > 50) ? 1 : 0;
}

// ---------------------------------------------------------------------------
struct Tab { const void* src[30]; int pref[31]; };

__global__ __launch_bounds__(256) void ingest_k(Tab tab, const int* __restrict__ flag,
                                                bf16* __restrict__ dst) {
    int idx = blockIdx.x * 256 + threadIdx.x;
    if (idx >= tab.pref[30]) return;
    int t = 0;
    while (tab.pref[t + 1] <= idx) t++;
    int e = idx - tab.pref[t];
    float v;
    if (*flag) v = ((const float*)tab.src[t])[e];
    else       v = b2f(((const bf16*)tab.src[t])[e]);
    dst[idx] = __float2bfloat16(v);
}

// ---------------------------------------------------------------------------
// fused prep (blocks 0..127) + zero-padding weight transpose (blocks 128..)
// ---------------------------------------------------------------------------
struct TT { const bf16* src[11]; bf16* dst[11]; int srcK[11]; int dK[11]; int pref[12]; };

__global__ __launch_bounds__(256) void prep_trans_k(
    TT tt,
    const bf16* __restrict__ xc, const bf16* __restrict__ yc,
    const bf16* __restrict__ xt,
    const bf16* __restrict__ pos,
    bf16* __restrict__ xin32, bf16* __restrict__ xt32,
    float2* __restrict__ posf2) {
    if (blockIdx.x < 128) {
        int row = blockIdx.x * 256 + threadIdx.x;
        bf16 z = __float2bfloat16(0.f);
        bf16* xr = xin32 + row * 32;
        xr[0] = xc[row * 2 + 0];
        xr[1] = xc[row * 2 + 1];
        xr[2] = yc[row * 3 + 0];
        xr[3] = yc[row * 3 + 1];
        xr[4] = yc[row * 3 + 2];
#pragma unroll
        for (int k = 5; k < 32; ++k) xr[k] = z;
        bf16* tr = xt32 + row * 32;
        tr[0] = xt[row * 2 + 0];
        tr[1] = xt[row * 2 + 1];
#pragma unroll
        for (int k = 2; k < 32; ++k) tr[k] = z;
        if (row < NNODE) posf2[row] = make_float2(b2f(pos[2 * row]), b2f(pos[2 * row + 1]));
        return;
    }
    int idx = (blockIdx.x - 128) * 256 + threadIdx.x;
    if (idx >= tt.pref[11]) return;
    int t = 0;
    while (tt.pref[t + 1] <= idx) t++;
    int e = idx - tt.pref[t];
    int k = e >> 7, n = e & 127;
    bf16 v = (k < tt.srcK[t]) ? tt.src[t][k * 128 + n] : __float2bfloat16(0.f);
    tt.dst[t][n * tt.dK[t] + k] = v;
}

// ---------------------------------------------------------------------------
__global__ __launch_bounds__(1024) void build_csr_k(const int* __restrict__ recv,
                                                    const int* __restrict__ send,
                                                    int* __restrict__ rowptr,
                                                    int* __restrict__ csr_send) {
    __shared__ int cnt[1024];
    __shared__ int wt[16], wt2[16];
    __shared__ int cur[1024];
    int t = threadIdx.x;
    cnt[t] = 0;
    __syncthreads();
    for (int e = t; e < NEDGE; e += 1024) atomicAdd(&cnt[recv[e]], 1);
    __syncthreads();
    int v = cnt[t];
    int lane = t & 63, w = t >> 6;
#pragma unroll
    for (int off = 1; off < 64; off <<= 1) {
        int u = __shfl_up(v, off);
        if (lane >= off) v += u;
    }
    if (lane == 63) wt[w] = v;
    __syncthreads();
    if (t < 16) {
        int x = wt[t];
#pragma unroll
        for (int off = 1; off < 16; off <<= 1) {
            int u = __shfl_up(x, off);
            if (t >= off) x += u;
        }
        wt2[t] = x;
    }
    __syncthreads();
    int excl = v - cnt[t] + (w ? wt2[w - 1] : 0);
    rowptr[t] = excl;
    cur[t] = excl;
    if (t == 0) rowptr[1024] = NEDGE;
    __syncthreads();
    for (int e = t; e < NEDGE; e += 1024) {
        int pos = atomicAdd(&cur[recv[e]], 1);
        csr_send[pos] = send[e];
    }
}

// ---------------------------------------------------------------------------
// COOPERATIVE fused recurrence: msg0 -> (EG -> node+msg)x3 -> EG -> final node.
// Grid 256 blocks x 512 threads (co-resident, 1 block/CU). 8 grid.sync()s
// replace 8 launch boundaries. GEMM phases: 32 rows/block, waves split 2(row)
// x 4(col); LN / vstat row-sums combine 4 partials via lnp[]. EG: 4 tasks/wave.
// ---------------------------------------------------------------------------
struct RecurArgs {
    float* lat0; float* lat1; bf16* inbox; bf16* PQ; float2* vstat;
    const bf16* WtMsg; const bf16* msg_b; const bf16* ln1_g; const bf16* ln1_b;
    const bf16* WtNode; const bf16* node_b; const bf16* ln2_g; const bf16* ln2_b;
    const int* rowptr; const int* csr_send; bf16* latT;
};

__global__ __launch_bounds__(512, 1) void recur_k(RecurArgs A) {
    cg::grid_group grid = cg::this_grid();
    __shared__ __align__(16) short Bs[8][64][8];
    __shared__ __align__(16) short Act[32][136];
    __shared__ float2 lnp[8][4][4];
    int tid = threadIdx.x;
    int w = tid >> 6, l = tid & 63;
    int lm = l & 15, lq = l >> 4;
    int wr = w & 1, wc = w >> 1;
    size_t row0 = (size_t)blockIdx.x * 32;

    auto stageB = [&](const bf16* W, int K, int k0) {
        int nt = tid >> 6, ll = tid & 63;
        *(short8*)&Bs[nt][ll][0] =
            ld_frag(W + (size_t)(nt * 16 + (ll & 15)) * K + k0 + (ll >> 4) * 8);
    };

    // msg GEMM (K=128, two 128-col halves). A from lat f32 (step0) or Act.
    auto msg_phase = [&](const float* curf, bool fromAct) {
        for (int half = 0; half < 2; ++half) {
            f32x4 acc[2];
            acc[0] = (f32x4){0.f,0.f,0.f,0.f}; acc[1] = (f32x4){0.f,0.f,0.f,0.f};
            for (int s = 0; s < 4; ++s) {
                int k0 = s * 32;
                __syncthreads();
                stageB(A.WtMsg + half * 16384, 128, k0);
                __syncthreads();
                short8 a;
                if (fromAct) a = *(const short8*)&Act[wr * 16 + lm][k0 + lq * 8];
                else         a = ld_frag(curf + (row0 + wr * 16 + lm) * 128 + k0 + lq * 8);
#pragma unroll
                for (int t2 = 0; t2 < 2; ++t2) {
                    short8 b = *(const short8*)&Bs[wc * 2 + t2][l][0];
                    acc[t2] = __builtin_amdgcn_mfma_f32_16x16x32_bf16(a, b, acc[t2], 0, 0, 0);
                }
            }
#pragma unroll
            for (int t2 = 0; t2 < 2; ++t2)
#pragma unroll
                for (int r = 0; r < 4; ++r)
                    A.PQ[(row0 + wr * 16 + lq * 4 + r) * 256 + half * 128 + wc * 32 + t2 * 16 + lm] =
                        __float2bfloat16(acc[t2][r]);
            if (half == 1) {
#pragma unroll
                for (int r = 0; r < 4; ++r) {
                    float s1 = 0.f, s2 = 0.f;
#pragma unroll
                    for (int t2 = 0; t2 < 2; ++t2) {
                        float vv = bs2f((short)f2bs(acc[t2][r]));
                        s1 += vv; s2 += vv * vv;
                    }
#pragma unroll
                    for (int m = 1; m < 16; m <<= 1) { s1 += __shfl_xor(s1, m); s2 += __shfl_xor(s2, m); }
                    if (lm == 0) lnp[w][lq][r] = make_float2(s1, s2);
                }
                __syncthreads();
                if (wc == 0 && lm == 0) {
#pragma unroll
                    for (int r = 0; r < 4; ++r) {
                        float S1 = 0.f, S2 = 0.f;
#pragma unroll
                        for (int j = 0; j < 4; ++j) {
                            float2 p = lnp[wr + 2 * j][lq][r];
                            S1 += p.x; S2 += p.y;
                        }
                        A.vstat[row0 + wr * 16 + lq * 4 + r] = make_float2(S1 * (1.f / 128.f), S2);
                    }
                }
            }
        }
    };

    // node GEMM K=256 (cur f32 | inbox bf16) + bias + LN; write nxt+Act or latT.
    auto node_phase = [&](const float* curf, float* nxtf, bool toLatT) {
        f32x4 acc[2];
        acc[0] = (f32x4){0.f,0.f,0.f,0.f}; acc[1] = (f32x4){0.f,0.f,0.f,0.f};
        for (int s = 0; s < 8; ++s) {
            int k0 = s * 32;
            __syncthreads();
            stageB(A.WtNode, 256, k0);
            __syncthreads();
            short8 a;
            if (k0 < 128) a = ld_frag(curf + (row0 + wr * 16 + lm) * 128 + k0 + lq * 8);
            else          a = ld_frag(A.inbox + (row0 + wr * 16 + lm) * 128 + (k0 - 128) + lq * 8);
#pragma unroll
            for (int t2 = 0; t2 < 2; ++t2) {
                short8 b = *(const short8*)&Bs[wc * 2 + t2][l][0];
                acc[t2] = __builtin_amdgcn_mfma_f32_16x16x32_bf16(a, b, acc[t2], 0, 0, 0);
            }
        }
        float v[2][4];
#pragma unroll
        for (int t2 = 0; t2 < 2; ++t2) {
            float bb = b2f(A.node_b[wc * 32 + t2 * 16 + lm]);
#pragma unroll
            for (int r = 0; r < 4; ++r) v[t2][r] = acc[t2][r] + bb;
        }
#pragma unroll
        for (int r = 0; r < 4; ++r) {
            float s1 = v[0][r] + v[1][r];
            float s2 = v[0][r] * v[0][r] + v[1][r] * v[1][r];
#pragma unroll
            for (int m = 1; m < 16; m <<= 1) { s1 += __shfl_xor(s1, m); s2 += __shfl_xor(s2, m); }
            if (lm == 0) lnp[w][lq][r] = make_float2(s1, s2);
        }
        __syncthreads();
#pragma unroll
        for (int r = 0; r < 4; ++r) {
            float S1 = 0.f, S2 = 0.f;
#pragma unroll
            for (int j = 0; j < 4; ++j) {
                float2 p = lnp[wr + 2 * j][lq][r];
                S1 += p.x; S2 += p.y;
            }
            float mu = S1 * (1.f / 128.f);
            float var = S2 * (1.f / 128.f) - mu * mu;
            float rs = rsqrtf(var + 1e-5f);
#pragma unroll
            for (int t2 = 0; t2 < 2; ++t2) {
                int n = wc * 32 + t2 * 16 + lm;
                v[t2][r] = (v[t2][r] - mu) * rs * b2f(A.ln2_g[n]) + b2f(A.ln2_b[n]);
            }
        }
        if (!toLatT) {
#pragma unroll
            for (int t2 = 0; t2 < 2; ++t2)
#pragma unroll
                for (int r = 0; r < 4; ++r) {
                    nxtf[(row0 + wr * 16 + lq * 4 + r) * 128 + wc * 32 + t2 * 16 + lm] = v[t2][r];
                    Act[wr * 16 + lq * 4 + r][wc * 32 + t2 * 16 + lm] = (short)f2bs(v[t2][r]);
                }
        } else {
            size_t grow = row0 + wr * 16 + lq * 4;
            int bb2 = (int)(grow >> 10);
            size_t rloc = grow & 1023;
#pragma unroll
            for (int t2 = 0; t2 < 2; ++t2) {
                int col = wc * 32 + t2 * 16 + lm;
                ushort4 u;
                u.x = f2bs(v[t2][0]); u.y = f2bs(v[t2][1]);
                u.z = f2bs(v[t2][2]); u.w = f2bs(v[t2][3]);
                *(ushort4*)(A.latT + ((size_t)bb2 * 128 + col) * (size_t)LDL + rloc) = u;
            }
        }
    };

    // edge gather: closed-form LN, 4 (b,n) tasks per wave.
    auto eg = [&]() {
        for (int it = 0; it < 4; ++it) {
            int gw = blockIdx.x * 8 + w + it * 2048;
            int b = gw >> 10, n = gw & 1023;
            const bf16* pqb = A.PQ + ((size_t)b << 18);
            const float2* vsb = A.vstat + b * NNODE;
            float u0 = b2f(pqb[(n << 8) + l]) + b2f(A.msg_b[l]);
            float u1 = b2f(pqb[(n << 8) + l + 64]) + b2f(A.msg_b[l + 64]);
            float g0 = b2f(A.ln1_g[l]), g1v = b2f(A.ln1_g[l + 64]);
            float bb0 = b2f(A.ln1_b[l]), bb1 = b2f(A.ln1_b[l + 64]);
            float s1 = u0 + u1, s2 = u0 * u0 + u1 * u1;
#pragma unroll
            for (int off = 32; off; off >>= 1) {
                s1 += __shfl_xor(s1, off);
                s2 += __shfl_xor(s2, off);
            }
            float aN = s1 * (1.f / 128.f);
            float Su = s2;
            int beg = A.rowptr[n], end = A.rowptr[n + 1];
            float R = 0.f, M = 0.f, t0 = 0.f, t1 = 0.f;
            int i = beg;
            for (; i + 1 < end; i += 2) {
                int sA = A.csr_send[i], sB = A.csr_send[i + 1];
                const bf16* qA = pqb + (sA << 8) + 128;
                const bf16* qB = pqb + (sB << 8) + 128;
                float vA0 = b2f(qA[l]), vA1 = b2f(qA[l + 64]);
                float vB0 = b2f(qB[l]), vB1 = b2f(qB[l + 64]);
                float dA = u0 * vA0 + u1 * vA1;
                float dB = u0 * vB0 + u1 * vB1;
#pragma unroll
                for (int off = 32; off; off >>= 1) {
                    dA += __shfl_xor(dA, off);
                    dB += __shfl_xor(dB, off);
                }
                float2 stA = vsb[sA];
                float2 stB = vsb[sB];
                float muA = aN + stA.x;
                float varA = (Su + stA.y + 2.f * dA) * (1.f / 128.f) - muA * muA;
                float rsA = rsqrtf(varA + 1e-5f);
                float muB = aN + stB.x;
                float varB = (Su + stB.y + 2.f * dB) * (1.f / 128.f) - muB * muB;
                float rsB = rsqrtf(varB + 1e-5f);
                R += rsA + rsB;
                M += rsA * muA + rsB * muB;
                t0 += rsA * vA0 + rsB * vB0;
                t1 += rsA * vA1 + rsB * vB1;
            }
            if (i < end) {
                int s = A.csr_send[i];
                const bf16* q = pqb + (s << 8) + 128;
                float v0 = b2f(q[l]), v1 = b2f(q[l + 64]);
                float d = u0 * v0 + u1 * v1;
#pragma unroll
                for (int off = 32; off; off >>= 1) d += __shfl_xor(d, off);
                float2 st = vsb[s];
                float mu = aN + st.x;
                float var = (Su + st.y + 2.f * d) * (1.f / 128.f) - mu * mu;
                float rs = rsqrtf(var + 1e-5f);
                R += rs;
                M += rs * mu;
                t0 += rs * v0;
                t1 += rs * v1;
            }
            float deg = (float)(end - beg);
            float a0 = g0 * (u0 * R + t0 - M) + deg * bb0;
            float a1 = g1v * (u1 * R + t1 - M) + deg * bb1;
            bf16* inb = A.inbox + ((size_t)b << 17) + (n << 7);
            inb[l] = __float2bfloat16(a0);
            inb[l + 64] = __float2bfloat16(a1);
        }
    };

    msg_phase(A.lat0, false);
    grid.sync();
    eg();
    grid.sync();
    node_phase(A.lat0, A.lat1, false);
    msg_phase(nullptr, true);
    grid.sync();
    eg();
    grid.sync();
    node_phase(A.lat1, A.lat0, false);
    msg_phase(nullptr, true);
    grid.sync();
    eg();
    grid.sync();
    node_phase(A.lat0, A.lat1, false);
    msg_phase(nullptr, true);
    grid.sync();
    eg();
    grid.sync();
    node_phase(A.lat1, nullptr, true);
}

// ---------------------------------------------------------------------------
// FUSED per-row MLP (encoder, 3 layers). Single in-place Act tile.
// ---------------------------------------------------------------------------
template <int K0STEPS, int LAYERS, int RELU_LAST, int TRANS, typename TIN, typename TOUT>
__global__ __launch_bounds__(256) void mlp_k(
    const TIN* __restrict__ Xa, const TIN* __restrict__ Xb, int ldx,
    const bf16* __restrict__ Wt0, const bf16* __restrict__ b0,
    const bf16* __restrict__ Wt1, const bf16* __restrict__ b1,
    const bf16* __restrict__ Wt2, const bf16* __restrict__ b2,
    TOUT* __restrict__ Y, int ldy, int tshift, int ldt)
{
    constexpr int K0 = K0STEPS * 32;
    __shared__ __align__(16) short Bs[8][64][8];
    __shared__ __align__(16) short Act[64][136];
    int tid = threadIdx.x;
    int w = tid >> 6, l = tid & 63;
    int lm = l & 15, lq = l >> 4;
    size_t row0 = (size_t)blockIdx.x * 64;

    f32x4 acc[8];
#pragma unroll
    for (int i = 0; i < 8; i++) acc[i] = (f32x4){0.f, 0.f, 0.f, 0.f};

    for (int s = 0; s < K0STEPS; ++s) {
        int k0 = s * 32;
        __syncthreads();
        short8 a;
        {
            const TIN* src = Xa; int kk = k0; int ld = ldx;
            if (Xb != nullptr && k0 >= 128) { src = Xb; kk = k0 - 128; ld = 128; }
            a = ld_frag(src + (row0 + w * 16 + lm) * (size_t)ld + kk + lq * 8);
        }
#pragma unroll
        for (int rr = 0; rr < 2; ++rr) {
            int idx = rr * 256 + tid;
            int nt = idx >> 6, ll = idx & 63;
            *(short8*)&Bs[nt][ll][0] =
                ld_frag(Wt0 + (size_t)(nt * 16 + (ll & 15)) * K0 + k0 + (ll >> 4) * 8);
        }
        __syncthreads();
#pragma unroll
        for (int nt = 0; nt < 8; ++nt) {
            short8 b = *(const short8*)&Bs[nt][l][0];
            acc[nt] = __builtin_amdgcn_mfma_f32_16x16x32_bf16(a, b, acc[nt], 0, 0, 0);
        }
    }
#pragma unroll
    for (int nt = 0; nt < 8; ++nt) {
        float bb = b2f(b0[nt * 16 + lm]);
#pragma unroll
        for (int r = 0; r < 4; ++r) {
            float x = fmaxf(acc[nt][r] + bb, 0.f);
            Act[w * 16 + lq * 4 + r][nt * 16 + lm] = (short)f2bs(x);
        }
    }

    for (int L = 1; L < LAYERS; ++L) {
        const bf16* Wt = (L == 1) ? Wt1 : Wt2;
        const bf16* bias = (L == 1) ? b1 : b2;
        bool last = (L == LAYERS - 1);
#pragma unroll
        for (int i = 0; i < 8; i++) acc[i] = (f32x4){0.f, 0.f, 0.f, 0.f};
        for (int s = 0; s < 4; ++s) {
            int k0 = s * 32;
            __syncthreads();
#pragma unroll
            for (int rr = 0; rr < 2; ++rr) {
                int idx = rr * 256 + tid;
                int nt = idx >> 6, ll = idx & 63;
                *(short8*)&Bs[nt][ll][0] =
                    ld_frag(Wt + (size_t)(nt * 16 + (ll & 15)) * 128 + k0 + (ll >> 4) * 8);
            }
            __syncthreads();
            short8 a = *(const short8*)&Act[w * 16 + lm][k0 + lq * 8];
#pragma unroll
            for (int nt = 0; nt < 8; ++nt) {
                short8 b = *(const short8*)&Bs[nt][l][0];
                acc[nt] = __builtin_amdgcn_mfma_f32_16x16x32_bf16(a, b, acc[nt], 0, 0, 0);
            }
        }
        if (!last) {
            __syncthreads();
#pragma unroll
            for (int nt = 0; nt < 8; ++nt) {
                float bb = b2f(bias[nt * 16 + lm]);
#pragma unroll
                for (int r = 0; r < 4; ++r) {
                    float x = fmaxf(acc[nt][r] + bb, 0.f);
                    Act[w * 16 + lq * 4 + r][nt * 16 + lm] = (short)f2bs(x);
                }
            }
        } else {
            float v[8][4];
#pragma unroll
            for (int nt = 0; nt < 8; ++nt) {
                float bb = b2f(bias[nt * 16 + lm]);
#pragma unroll
                for (int r = 0; r < 4; ++r) {
                    float x = acc[nt][r] + bb;
                    if (RELU_LAST) x = fmaxf(x, 0.f);
                    v[nt][r] = x;
                }
            }
            if constexpr (TRANS) {
                size_t grow = row0 + w * 16 + lq * 4;
                int bb2 = (int)(grow >> tshift);
                size_t rloc = grow & (((size_t)1 << tshift) - 1);
                bf16* YT = (bf16*)Y;
#pragma unroll
                for (int nt = 0; nt < 8; ++nt) {
                    int col = nt * 16 + lm;
                    ushort4 u;
                    u.x = f2bs(v[nt][0]); u.y = f2bs(v[nt][1]);
                    u.z = f2bs(v[nt][2]); u.w = f2bs(v[nt][3]);
                    *(ushort4*)(YT + ((size_t)bb2 * 128 + col) * (size_t)ldt + rloc) = u;
                }
            } else {
#pragma unroll
                for (int nt = 0; nt < 8; ++nt)
#pragma unroll
                    for (int r = 0; r < 4; ++r)
                        Y[(row0 + w * 16 + lq * 4 + r) * (size_t)ldy + nt * 16 + lm] =
                            Cvt<TOUT>::to(v[nt][r]);
            }
        }
    }
}

// ---------------------------------------------------------------------------
// FUSED tail: qenc (3 layers) -> q in Act; dec L0 (z|q), dec L1, final 128->3.
// ---------------------------------------------------------------------------
__global__ __launch_bounds__(256) void qdec_k(
    const bf16* __restrict__ xt32,
    const bf16* __restrict__ WtQ0, const bf16* __restrict__ qb0,
    const bf16* __restrict__ WtQ1, const bf16* __restrict__ qb1,
    const bf16* __restrict__ WtQ2, const bf16* __restrict__ qb2,
    const bf16* __restrict__ z,
    const bf16* __restrict__ WtDec0, const bf16* __restrict__ db0,
    const bf16* __restrict__ WtDec1, const bf16* __restrict__ db1,
    const bf16* __restrict__ W2, const bf16* __restrict__ b2v,
    const int* __restrict__ flag, void* __restrict__ out)
{
    __shared__ __align__(16) short Bs[8][64][8];
    __shared__ __align__(16) short Act[64][136];
    __shared__ bf16 w2s[384];
    int tid = threadIdx.x;
    int w = tid >> 6, l = tid & 63;
    int lm = l & 15, lq = l >> 4;
    size_t row0 = (size_t)blockIdx.x * 64;
    for (int t = tid; t < 384; t += 256) w2s[t] = W2[t];

    f32x4 acc[8];
#pragma unroll
    for (int i = 0; i < 8; i++) acc[i] = (f32x4){0.f, 0.f, 0.f, 0.f};

    // qenc L0 (K=32)
    {
        __syncthreads();
#pragma unroll
        for (int rr = 0; rr < 2; ++rr) {
            int idx = rr * 256 + tid;
            int nt = idx >> 6, ll = idx & 63;
            *(short8*)&Bs[nt][ll][0] =
                ld_frag(WtQ0 + (size_t)(nt * 16 + (ll & 15)) * 32 + (ll >> 4) * 8);
        }
        __syncthreads();
        short8 a = ld_frag(xt32 + (row0 + w * 16 + lm) * 32 + lq * 8);
#pragma unroll
        for (int nt = 0; nt < 8; ++nt) {
            short8 b = *(const short8*)&Bs[nt][l][0];
            acc[nt] = __builtin_amdgcn_mfma_f32_16x16x32_bf16(a, b, acc[nt], 0, 0, 0);
        }
#pragma unroll
        for (int nt = 0; nt < 8; ++nt) {
            float bb = b2f(qb0[nt * 16 + lm]);
#pragma unroll
            for (int r = 0; r < 4; ++r)
                Act[w * 16 + lq * 4 + r][nt * 16 + lm] = (short)f2bs(fmaxf(acc[nt][r] + bb, 0.f));
        }
    }
    // qenc L1 (relu) and L2 (no relu) -> Act
    for (int L = 1; L < 3; ++L) {
        const bf16* Wt = (L == 1) ? WtQ1 : WtQ2;
        const bf16* bias = (L == 1) ? qb1 : qb2;
#pragma unroll
        for (int i = 0; i < 8; i++) acc[i] = (f32x4){0.f, 0.f, 0.f, 0.f};
        for (int s = 0; s < 4; ++s) {
            int k0 = s * 32;
            __syncthreads();
#pragma unroll
            for (int rr = 0; rr < 2; ++rr) {
                int idx = rr * 256 + tid;
                int nt = idx >> 6, ll = idx & 63;
                *(short8*)&Bs[nt][ll][0] =
                    ld_frag(Wt + (size_t)(nt * 16 + (ll & 15)) * 128 + k0 + (ll >> 4) * 8);
            }
            __syncthreads();
            short8 a = *(const short8*)&Act[w * 16 + lm][k0 + lq * 8];
#pragma unroll
            for (int nt = 0; nt < 8; ++nt) {
                short8 b = *(const short8*)&Bs[nt][l][0];
                acc[nt] = __builtin_amdgcn_mfma_f32_16x16x32_bf16(a, b, acc[nt], 0, 0, 0);
            }
        }
        __syncthreads();
#pragma unroll
        for (int nt = 0; nt < 8; ++nt) {
            float bb = b2f(bias[nt * 16 + lm]);
#pragma unroll
            for (int r = 0; r < 4; ++r) {
                float x = acc[nt][r] + bb;
                if (L == 1) x = fmaxf(x, 0.f);
                Act[w * 16 + lq * 4 + r][nt * 16 + lm] = (short)f2bs(x);
            }
        }
    }
    // dec L0: K=256 = z (global) | q (Act); relu -> Act
    {
#pragma unroll
        for (int i = 0; i < 8; i++) acc[i] = (f32x4){0.f, 0.f, 0.f, 0.f};
        for (int s = 0; s < 8; ++s) {
            int k0 = s * 32;
            __syncthreads();
#pragma unroll
            for (int rr = 0; rr < 2; ++rr) {
                int idx = rr * 256 + tid;
                int nt = idx >> 6, ll = idx & 63;
                *(short8*)&Bs[nt][ll][0] =
                    ld_frag(WtDec0 + (size_t)(nt * 16 + (ll & 15)) * 256 + k0 + (ll >> 4) * 8);
            }
            __syncthreads();
            short8 a;
            if (k0 < 128) a = ld_frag(z + (row0 + w * 16 + lm) * (size_t)128 + k0 + lq * 8);
            else          a = *(const short8*)&Act[w * 16 + lm][(k0 - 128) + lq * 8];
#pragma unroll
            for (int nt = 0; nt < 8; ++nt) {
                short8 b = *(const short8*)&Bs[nt][l][0];
                acc[nt] = __builtin_amdgcn_mfma_f32_16x16x32_bf16(a, b, acc[nt], 0, 0, 0);
            }
        }
        __syncthreads();
#pragma unroll
        for (int nt = 0; nt < 8; ++nt) {
            float bb = b2f(db0[nt * 16 + lm]);
#pragma unroll
            for (int r = 0; r < 4; ++r)
                Act[w * 16 + lq * 4 + r][nt * 16 + lm] = (short)f2bs(fmaxf(acc[nt][r] + bb, 0.f));
        }
    }
    // dec L1: K=128 from Act; relu -> Act
    {
#pragma unroll
        for (int i = 0; i < 8; i++) acc[i] = (f32x4){0.f, 0.f, 0.f, 0.f};
        for (int s = 0; s < 4; ++s) {
            int k0 = s * 32;
            __syncthreads();
#pragma unroll
            for (int rr = 0; rr < 2; ++rr) {
                int idx = rr * 256 + tid;
                int nt = idx >> 6, ll = idx & 63;
                *(short8*)&Bs[nt][ll][0] =
                    ld_frag(WtDec1 + (size_t)(nt * 16 + (ll & 15)) * 128 + k0 + (ll >> 4) * 8);
            }
            __syncthreads();
            short8 a = *(const short8*)&Act[w * 16 + lm][k0 + lq * 8];
#pragma unroll
            for (int nt = 0; nt < 8; ++nt) {
                short8 b = *(const short8*)&Bs[nt][l][0];
                acc[nt] = __builtin_amdgcn_mfma_f32_16x16x32_bf16(a, b, acc[nt], 0, 0, 0);
            }
        }
        __syncthreads();
#pragma unroll
        for (int nt = 0; nt < 8; ++nt) {
            float bb = b2f(db1[nt * 16 + lm]);
#pragma unroll
            for (int r = 0; r < 4; ++r)
                Act[w * 16 + lq * 4 + r][nt * 16 + lm] = (short)f2bs(fmaxf(acc[nt][r] + bb, 0.f));
        }
    }
    __syncthreads();
    // final 128 -> 3
    if (tid < 192) {
        int row = tid / 3, col = tid - (tid / 3) * 3;
        float a = b2f(b2v[col]);
        for (int k8 = 0; k8 < 16; ++k8) {
            short8 av = *(const short8*)&Act[row][k8 * 8];
#pragma unroll
            for (int j = 0; j < 8; ++j)
                a += bs2f(av[j]) * b2f(w2s[(k8 * 8 + j) * 3 + col]);
        }
        size_t o = (row0 + row) * 3 + col;
        if (*flag) ((float*)out)[o] = a;
        else       ((bf16*)out)[o] = __float2bfloat16(a);
    }
}

// ---------------------------------------------------------------------------
// fused softmax stats. v2: 4096 blocks x 4 quads (pos staged once per block).
// ---------------------------------------------------------------------------
__global__ __launch_bounds__(256) void stats2_k(const bf16* __restrict__ xcp,
                                                const bf16* __restrict__ xtp,
                                                const bf16* __restrict__ pos,
                                                float4* __restrict__ cstC4,
                                                float4* __restrict__ cstT4) {
    __shared__ float px[NNODE], py[NNODE];
    int tid = threadIdx.x;
    for (int t = tid; t < NNODE; t += 256) {
        px[t] = b2f(pos[2 * t]);
        py[t] = b2f(pos[2 * t + 1]);
    }
    __syncthreads();
    int w = tid >> 6, l = tid & 63;
#pragma unroll
    for (int it = 0; it < 4; ++it) {
        int qb = blockIdx.x + it * 4096;
        const bf16* xp = (qb < 8192) ? xcp : xtp;
        float4* st4 = (qb < 8192) ? cstC4 : cstT4;
        int pb = qb & 8191;
        int p = pb * 4 + w;
        float x = b2f(xp[2 * p]), y = b2f(xp[2 * p + 1]);
        float vals[16];
        float m = -3.4e38f;
#pragma unroll
        for (int k = 0; k < 16; k++) {
            int n = k * 64 + l;
            float dx = x - px[n], dy = y - py[n];
            float v = -(dx * dx + dy * dy);
            vals[k] = v;
            m = fmaxf(m, v);
        }
#pragma unroll
        for (int off = 32; off; off >>= 1) m = fmaxf(m, __shfl_xor(m, off));
        float s = 0.f;
#pragma unroll
        for (int k = 0; k < 16; k++) s += __expf(vals[k] - m);
#pragma unroll
        for (int off = 32; off; off >>= 1) s += __shfl_xor(s, off);
        if (l == 0) st4[p] = make_float4(x, y, m, 1.f / s);
    }
}

struct P8 { float* p[8]; };

// ---------------------------------------------------------------------------
// lat partials via MFMA. v2: cooperative LDS staging of emb chunks (dedup 4x),
// XOR-swizzled tile; up = K-step within the shared 64-col chunk.
// ---------------------------------------------------------------------------
__global__ __launch_bounds__(512, 4) void lat_mfma_k(const bf16* __restrict__ embT,
                                                     const float2* __restrict__ posf2,
                                                     const float4* __restrict__ cstC4,
                                                     P8 parts) {
    int i = blockIdx.x;
    int b = i & 7, r = i >> 3;
    int cs = r >> 4, nt = r & 15;
    int n0 = nt * 64;
    __shared__ __align__(16) float4 csh[512];
    __shared__ __align__(16) union ShU {
        short stage[2][8192];        // 2 x [128 rows][64 cols] bf16, swizzled
        float4 red[4][8][64];
    } sh;
    int tid = threadIdx.x;
    int w = tid >> 6, l = tid & 63;
    int wl = w & 3, up = w >> 2;
    int lm = l & 15, lq = l >> 4;
    int node = n0 + wl * 16 + lm;
    float2 pn = posf2[node];
    const bf16* ebase = embT + (size_t)b * (128 * LDE) + cs * 512;
    const float4* cbase = cstC4 + b * NC + cs * 512;
    csh[tid] = cbase[tid];

    int h0 = tid >> 3;
    int cb0 = (tid & 7) << 4;
    const char* g0 = (const char*)ebase + (size_t)h0 * (LDE * 2) + cb0;
    const size_t gH = (size_t)64 * (LDE * 2);
    int o0 = h0 * 128 + (cb0 ^ ((h0 & 7) << 4));   // swizzled LDS byte offset
    char* lbuf0 = (char*)&sh.stage[0][0];
    char* lbuf1 = (char*)&sh.stage[1][0];

    {
        uint4 rA = *(const uint4*)(g0);
        uint4 rB = *(const uint4*)(g0 + gH);
        *(uint4*)(lbuf0 + o0) = rA;
        *(uint4*)(lbuf0 + o0 + 64 * 128) = rB;
    }
    __syncthreads();

    f32x4 acc[8];
#pragma unroll
    for (int q = 0; q < 8; q++) acc[q] = (f32x4){0.f, 0.f, 0.f, 0.f};

    union AF { short8 s; u16 u[8]; };
    int rb = up * 64 + lq * 16;

    for (int ci = 0; ci < 8; ++ci) {
        char* cur = (ci & 1) ? lbuf1 : lbuf0;
        char* nxt = (ci & 1) ? lbuf0 : lbuf1;
        uint4 rA, rB;
        if (ci < 7) {
            const char* gs = g0 + (ci + 1) * 128;
            rA = *(const uint4*)(gs);
            rB = *(const uint4*)(gs + gH);
        }
        AF cw;
        int cidx = ci * 64 + up * 32 + lq * 8;
#pragma unroll
        for (int j = 0; j < 8; ++j) {
            float4 cc = csh[cidx + j];
            float dx = cc.x - pn.x, dy = cc.y - pn.y;
            cw.u[j] = f2bs(__expf(-(dx * dx + dy * dy) - cc.z) * cc.w);
        }
#pragma unroll
        for (int t2 = 0; t2 < 8; ++t2) {
            int h = t2 * 16 + lm;
            short8 bfr = *(const short8*)(cur + h * 128 + (rb ^ ((h & 7) << 4)));
            acc[t2] = __builtin_amdgcn_mfma_f32_16x16x32_bf16(cw.s, bfr, acc[t2], 0, 0, 0);
        }
        if (ci < 7) {
            *(uint4*)(nxt + o0) = rA;
            *(uint4*)(nxt + o0 + 64 * 128) = rB;
        }
        __syncthreads();
    }

    if (up) {
#pragma unroll
        for (int t2 = 0; t2 < 8; ++t2)
            sh.red[wl][t2][l] = make_float4(acc[t2][0], acc[t2][1], acc[t2][2], acc[t2][3]);
    }
    __syncthreads();
    if (!up) {
        float* part = parts.p[cs] + (((size_t)(b * NNODE + n0 + wl * 16 + lq * 4)) << 7) + lm;
#pragma unroll
        for (int t2 = 0; t2 < 8; ++t2) {
            float4 o = sh.red[wl][t2][l];
#pragma unroll
            for (int r2 = 0; r2 < 4; ++r2)
                part[(r2 << 7) + t2 * 16] = acc[t2][r2] + ((const float*)&o)[r2];
        }
    }
}

__global__ __launch_bounds__(256) void reduce8_k(float* __restrict__ dst, P8 parts) {
    int i = blockIdx.x * 256 + threadIdx.x;
    float4 s = ((const float4*)parts.p[0])[i];
#pragma unroll
    for (int k = 1; k < 8; ++k) {
        float4 v = ((const float4*)parts.p[k])[i];
        s.x += v.x; s.y += v.y; s.z += v.z; s.w += v.w;
    }
    ((float4*)dst)[i] = s;
}

// ---------------------------------------------------------------------------
// z via MFMA. v2: same cooperative LDS staging as lat_mfma_k.
// ---------------------------------------------------------------------------
__global__ __launch_bounds__(512, 4) void z_mfma_k(const bf16* __restrict__ latT,
                                                   const float2* __restrict__ posf2,
                                                   const float4* __restrict__ cstT4,
                                                   bf16* __restrict__ z) {
    int i = blockIdx.x;
    int b = i & 7, tt = i >> 3;
    int t0 = tt * 64;
    __shared__ __align__(8) float2 posh[1024];
    __shared__ __align__(16) union ShU {
        short stage[2][8192];
        float4 red[4][8][64];
    } sh;
    int tid = threadIdx.x;
    int w = tid >> 6, l = tid & 63;
    int wl = w & 3, up = w >> 2;
    int lm = l & 15, lq = l >> 4;
    int t = t0 + wl * 16 + lm;
    float4 qs = cstT4[b * NTT + t];
    const bf16* lbase = latT + (size_t)b * (128 * LDL);
    for (int k = tid; k < 1024; k += 512) posh[k] = posf2[k];

    int h0 = tid >> 3;
    int cb0 = (tid & 7) << 4;
    const char* g0 = (const char*)lbase + (size_t)h0 * (LDL * 2) + cb0;
    const size_t gH = (size_t)64 * (LDL * 2);
    int o0 = h0 * 128 + (cb0 ^ ((h0 & 7) << 4));
    char* lbuf0 = (char*)&sh.stage[0][0];
    char* lbuf1 = (char*)&sh.stage[1][0];

    {
        uint4 rA = *(const uint4*)(g0);
        uint4 rB = *(const uint4*)(g0 + gH);
        *(uint4*)(lbuf0 + o0) = rA;
        *(uint4*)(lbuf0 + o0 + 64 * 128) = rB;
    }
    __syncthreads();

    f32x4 acc[8];
#pragma unroll
    for (int q = 0; q < 8; q++) acc[q] = (f32x4){0.f, 0.f, 0.f, 0.f};

    union AF { short8 s; u16 u[8]; };
    int rb = up * 64 + lq * 16;

    for (int ci = 0; ci < 16; ++ci) {
        char* cur = (ci & 1) ? lbuf1 : lbuf0;
        char* nxt = (ci & 1) ? lbuf0 : lbuf1;
        uint4 rA, rB;
        if (ci < 15) {
            const char* gs = g0 + (ci + 1) * 128;
            rA = *(const uint4*)(gs);
            rB = *(const uint4*)(gs + gH);
        }
        AF cw;
        int cidx = ci * 64 + up * 32 + lq * 8;
#pragma unroll
        for (int j = 0; j < 8; ++j) {
            float2 pn = posh[cidx + j];
            float dx = qs.x - pn.x, dy = qs.y - pn.y;
            cw.u[j] = f2bs(__expf(-(dx * dx + dy * dy) - qs.z) * qs.w);
        }
#pragma unroll
        for (int t2 = 0; t2 < 8; ++t2) {
            int h = t2 * 16 + lm;
            short8 bfr = *(const short8*)(cur + h * 128 + (rb ^ ((h & 7) << 4)));
            acc[t2] = __builtin_amdgcn_mfma_f32_16x16x32_bf16(cw.s, bfr, acc[t2], 0, 0, 0);
        }
        if (ci < 15) {
            *(uint4*)(nxt + o0) = rA;
            *(uint4*)(nxt + o0 + 64 * 128) = rB;
        }
        __syncthreads();
    }

    if (up) {
#pragma unroll
        for (int t2 = 0; t2 < 8; ++t2)
            sh.red[wl][t2][l] = make_float4(acc[t2][0], acc[t2][1], acc[t2][2], acc[t2][3]);
    }
    __syncthreads();
    if (!up) {
        bf16* zp = z + (((size_t)(b * NTT + t0 + wl * 16 + lq * 4)) << 7) + lm;
#pragma unroll
        for (int t2 = 0; t2 < 8; ++t2) {
            float4 o = sh.red[wl][t2][l];
#pragma unroll
            for (int r2 = 0; r2 < 4; ++r2)
                zp[(r2 << 7) + t2 * 16] = __float2bfloat16(acc[t2][r2] + ((const float*)&o)[r2]);
        }
    }
}

// ---------------------------------------------------------------------------
extern "C" void kernel_launch(void* const* d_in, const int* in_sizes, int n_in,
                              void* d_out, int out_size, void* d_ws, size_t ws_size,
                              hipStream_t stream) {
    const int* senders = (const int*)d_in[30];
    const int* receivers = (const int*)d_in[31];

    char* base = (char*)d_ws;
    size_t off = 0;
    auto alloc = [&](size_t bytes) { char* p = base + off; off += (bytes + 255) & ~(size_t)255; return p; };

    int* flag = (int*)alloc(256);

    Tab tab;
    int pref = 0;
    for (int i = 0; i < 30; ++i) { tab.src[i] = d_in[i]; tab.pref[i] = pref; pref += in_sizes[i]; }
    tab.pref[30] = pref;
    bf16* arena = (bf16*)alloc((size_t)pref * 2);
    auto C = [&](int i) { return arena + tab.pref[i]; };

    float4* cstC4 = (float4*)alloc(32768 * sizeof(float4));
    float4* cstT4 = (float4*)alloc(32768 * sizeof(float4));
    float* lat0  = (float*)alloc(8192 * 128 * 4);
    float* lat1  = (float*)alloc(8192 * 128 * 4);
    float* inboxf = (float*)alloc(8192 * 128 * 4);          // lat partials only
    bf16* inbox  = (bf16*)alloc(8192 * 128 * 2);            // bf16 inbox
    bf16* T1     = (bf16*)alloc((size_t)32768 * 128 * 2);
    bf16* T2     = (bf16*)alloc((size_t)32768 * 128 * 2);
    bf16* T3     = (bf16*)alloc((size_t)32768 * 128 * 2);
    bf16* embT   = (bf16*)alloc((size_t)8 * 128 * LDE * 2);
    bf16* latT   = (bf16*)alloc((size_t)8 * 128 * LDL * 2);
    bf16* xin32  = (bf16*)alloc((size_t)32768 * 32 * 2);
    bf16* xt32   = (bf16*)alloc((size_t)32768 * 32 * 2);
    float2* posf2 = (float2*)alloc(1024 * sizeof(float2));
    float2* vstat = (float2*)alloc(8192 * sizeof(float2));
    int* rowptr  = (int*)alloc(1025 * 4);
    int* csr_send = (int*)alloc(NEDGE * 4);
    bf16* WtEnc0 = (bf16*)alloc(128 * 32 * 2);
    bf16* WtQ0   = (bf16*)alloc(128 * 32 * 2);
    bf16* WtEnc1 = (bf16*)alloc(16384 * 2);
    bf16* WtEnc2 = (bf16*)alloc(16384 * 2);
    bf16* WtQ1   = (bf16*)alloc(16384 * 2);
    bf16* WtQ2   = (bf16*)alloc(16384 * 2);
    bf16* WtDec0 = (bf16*)alloc(32768 * 2);
    bf16* WtDec1 = (bf16*)alloc(16384 * 2);
    bf16* WtMsg  = (bf16*)alloc(32768 * 2);
    bf16* WtNode = (bf16*)alloc(32768 * 2);
    bf16* PQ     = T3;   // overlay: bf16 PQ (4 MB) in T3's region; disjoint lifetime
    (void)ws_size; (void)n_in; (void)out_size;

    detect_k<<<1, 256, 0, stream>>>((const u16*)d_in[3], flag);
    ingest_k<<<(pref + 255) / 256, 256, 0, stream>>>(tab, flag, arena);

    const bf16 *xc = C(0), *yc = C(1), *xt = C(2), *pos = C(3);
    const bf16 *enc_W0 = C(4), *enc_b0 = C(5), *enc_W1 = C(6), *enc_b1 = C(7), *enc_W2 = C(8), *enc_b2 = C(9);
    const bf16 *qenc_W0 = C(10), *qenc_b0 = C(11), *qenc_W1 = C(12), *qenc_b1 = C(13), *qenc_W2 = C(14), *qenc_b2 = C(15);
    const bf16 *dec_W0 = C(16), *dec_b0 = C(17), *dec_W1 = C(18), *dec_b1 = C(19), *dec_W2 = C(20), *dec_b2 = C(21);
    const bf16 *msg_W = C(22), *msg_b = C(23), *ln1_g = C(24), *ln1_b = C(25);
    const bf16 *node_W = C(26), *node_b = C(27), *ln2_g = C(28), *ln2_b = C(29);

    TT tt;
    const bf16* s11[11] = { enc_W1, enc_W2, qenc_W1, qenc_W2, dec_W1, dec_W0, msg_W, msg_W + 16384, node_W, enc_W0, qenc_W0 };
    bf16* d11[11]       = { WtEnc1, WtEnc2, WtQ1,    WtQ2,    WtDec1, WtDec0, WtMsg, WtMsg + 16384, WtNode, WtEnc0, WtQ0   };
    int sk11[11] = { 128, 128, 128, 128, 128, 256, 128, 128, 256, 5, 2 };
    int dk11[11] = { 128, 128, 128, 128, 128, 256, 128, 128, 256, 32, 32 };
    int tp = 0;
    for (int i = 0; i < 11; ++i) {
        tt.src[i] = s11[i]; tt.dst[i] = d11[i]; tt.srcK[i] = sk11[i]; tt.dK[i] = dk11[i];
        tt.pref[i] = tp; tp += dk11[i] * 128;
    }
    tt.pref[11] = tp;

    prep_trans_k<<<128 + (tp + 255) / 256, 256, 0, stream>>>(tt, xc, yc, xt, pos, xin32, xt32, posf2);
    build_csr_k<<<1, 1024, 0, stream>>>(receivers, senders, rowptr, csr_send);

    // encoder (fused 3-layer MLP): xin32 -> embT (transposed, padded rows)
    mlp_k<1, 3, 0, 1, bf16, bf16><<<512, 256, 0, stream>>>(
        xin32, nullptr, 32, WtEnc0, enc_b0, WtEnc1, enc_b1, WtEnc2, enc_b2, embT, 128, 12, LDE);

    stats2_k<<<4096, 256, 0, stream>>>(xc, xt, pos, cstC4, cstT4);

    P8 parts;
    parts.p[0] = lat1;
    parts.p[1] = inboxf;
    parts.p[2] = (float*)T1;
    parts.p[3] = (float*)T1 + 1048576;
    parts.p[4] = (float*)T2;
    parts.p[5] = (float*)T2 + 1048576;
    parts.p[6] = (float*)T3;
    parts.p[7] = (float*)T3 + 1048576;
    lat_mfma_k<<<1024, 512, 0, stream>>>(embT, posf2, cstC4, parts);
    reduce8_k<<<1024, 256, 0, stream>>>(lat0, parts);

    // 4-step recurrence fused into ONE cooperative kernel (was 9 launches)
    RecurArgs ra;
    ra.lat0 = lat0; ra.lat1 = lat1; ra.inbox = inbox; ra.PQ = PQ; ra.vstat = vstat;
    ra.WtMsg = WtMsg; ra.msg_b = msg_b; ra.ln1_g = ln1_g; ra.ln1_b = ln1_b;
    ra.WtNode = WtNode; ra.node_b = node_b; ra.ln2_g = ln2_g; ra.ln2_b = ln2_b;
    ra.rowptr = rowptr; ra.csr_send = csr_send; ra.latT = latT;
    void* kargs[] = { &ra };
    hipLaunchCooperativeKernel((void*)recur_k, dim3(256), dim3(512), kargs, 0, stream);

    // z -> T2 (bf16)
    z_mfma_k<<<512, 512, 0, stream>>>(latT, posf2, cstT4, T2);

    // fused tail: qenc(xt32) + dec(z|q) + final -> out
    qdec_k<<<512, 256, 0, stream>>>(xt32,
                                    WtQ0, qenc_b0, WtQ1, qenc_b1, WtQ2, qenc_b2,
                                    T2,
                                    WtDec0, dec_b0, WtDec1, dec_b1,
                                    dec_W2, dec_b2, flag, d_out);
}

// Round 11
// 394.737 us; speedup vs baseline: 1.8801x; 1.8801x over previous
//
#include <hip/hip_runtime.h>
#include <hip/hip_bf16.h>
#include <string.h>

#define BB 8
#define NC 4096
#define NTT 4096
#define NNODE 1024
#define NEDGE 16384
#define LDE 4128   // embT row-dim padded (+64B) to break 8KB power-of-2 stride
#define LDL 1056   // latT row-dim padded (+64B) to break 2KB power-of-2 stride

typedef __hip_bfloat16 bf16;
typedef unsigned short u16;
typedef __attribute__((ext_vector_type(8))) short short8;
typedef __attribute__((ext_vector_type(4))) float f32x4;

__device__ __forceinline__ float b2f(bf16 x) { return __bfloat162float(x); }
__device__ __forceinline__ float bs2f(short s) { return __uint_as_float(((unsigned)(unsigned short)s) << 16); }

template <typename T> struct Cvt;
template <> struct Cvt<float> { static __device__ __forceinline__ float to(float v) { return v; } };
template <> struct Cvt<bf16>  { static __device__ __forceinline__ bf16  to(float v) { return __float2bfloat16(v); } };

__device__ __forceinline__ unsigned short f2bs(float x) {
    unsigned u = __float_as_uint(x);
    return (unsigned short)((u + 0x7FFFu + ((u >> 16) & 1u)) >> 16);
}

__device__ __forceinline__ short8 ld_frag(const bf16* g) {
    union { uint4 u4; short8 s8; } cv;
    cv.u4 = *(const uint4*)g;
    return cv.s8;
}
__device__ __forceinline__ short8 ld_frag(const float* g) {
    float4 f0 = *(const float4*)g;
    float4 f1 = *(const float4*)(g + 4);
    short8 r;
    r[0] = (short)f2bs(f0.x); r[1] = (short)f2bs(f0.y);
    r[2] = (short)f2bs(f0.z); r[3] = (short)f2bs(f0.w);
    r[4] = (short)f2bs(f1.x); r[5] = (short)f2bs(f1.y);
    r[6] = (short)f2bs(f1.z); r[7] = (short)f2bs(f1.w);
    return r;
}

// ---------------------------------------------------------------------------
__global__ void detect_k(const u16* __restrict__ posu, int* __restrict__ flag) {
    __shared__ int cnt;
    if (threadIdx.x == 0) cnt = 0;
    __syncthreads();
    int wild = 0;
    for (int i = threadIdx.x; i < 1024; i += 256) {
        u16 u = posu[2 * i];
        int ex = (u >> 7) & 0xFF;
        if (ex == 0 || ex == 0xFF || ex > 137 || ex < 107) wild++;
    }
    atomicAdd(&cnt, wild);
    __syncthreads();
    if (threadIdx.x == 0) *flag = (cnt > 50) ? 1 : 0;
}

// ---------------------------------------------------------------------------
struct Tab { const void* src[30]; int pref[31]; };

__global__ __launch_bounds__(256) void ingest_k(Tab tab, const int* __restrict__ flag,
                                                bf16* __restrict__ dst) {
    int idx = blockIdx.x * 256 + threadIdx.x;
    if (idx >= tab.pref[30]) return;
    int t = 0;
    while (tab.pref[t + 1] <= idx) t++;
    int e = idx - tab.pref[t];
    float v;
    if (*flag) v = ((const float*)tab.src[t])[e];
    else       v = b2f(((const bf16*)tab.src[t])[e]);
    dst[idx] = __float2bfloat16(v);
}

// ---------------------------------------------------------------------------
// fused prep (blocks 0..127) + zero-padding weight transpose (blocks 128..)
// ---------------------------------------------------------------------------
struct TT { const bf16* src[11]; bf16* dst[11]; int srcK[11]; int dK[11]; int pref[12]; };

__global__ __launch_bounds__(256) void prep_trans_k(
    TT tt,
    const bf16* __restrict__ xc, const bf16* __restrict__ yc,
    const bf16* __restrict__ xt,
    const bf16* __restrict__ pos,
    bf16* __restrict__ xin32, bf16* __restrict__ xt32,
    float2* __restrict__ posf2) {
    if (blockIdx.x < 128) {
        int row = blockIdx.x * 256 + threadIdx.x;
        bf16 z = __float2bfloat16(0.f);
        bf16* xr = xin32 + row * 32;
        xr[0] = xc[row * 2 + 0];
        xr[1] = xc[row * 2 + 1];
        xr[2] = yc[row * 3 + 0];
        xr[3] = yc[row * 3 + 1];
        xr[4] = yc[row * 3 + 2];
#pragma unroll
        for (int k = 5; k < 32; ++k) xr[k] = z;
        bf16* tr = xt32 + row * 32;
        tr[0] = xt[row * 2 + 0];
        tr[1] = xt[row * 2 + 1];
#pragma unroll
        for (int k = 2; k < 32; ++k) tr[k] = z;
        if (row < NNODE) posf2[row] = make_float2(b2f(pos[2 * row]), b2f(pos[2 * row + 1]));
        return;
    }
    int idx = (blockIdx.x - 128) * 256 + threadIdx.x;
    if (idx >= tt.pref[11]) return;
    int t = 0;
    while (tt.pref[t + 1] <= idx) t++;
    int e = idx - tt.pref[t];
    int k = e >> 7, n = e & 127;
    bf16 v = (k < tt.srcK[t]) ? tt.src[t][k * 128 + n] : __float2bfloat16(0.f);
    tt.dst[t][n * tt.dK[t] + k] = v;
}

// ---------------------------------------------------------------------------
__global__ __launch_bounds__(1024) void build_csr_k(const int* __restrict__ recv,
                                                    const int* __restrict__ send,
                                                    int* __restrict__ rowptr,
                                                    int* __restrict__ csr_send) {
    __shared__ int cnt[1024];
    __shared__ int wt[16], wt2[16];
    __shared__ int cur[1024];
    int t = threadIdx.x;
    cnt[t] = 0;
    __syncthreads();
    for (int e = t; e < NEDGE; e += 1024) atomicAdd(&cnt[recv[e]], 1);
    __syncthreads();
    int v = cnt[t];
    int lane = t & 63, w = t >> 6;
#pragma unroll
    for (int off = 1; off < 64; off <<= 1) {
        int u = __shfl_up(v, off);
        if (lane >= off) v += u;
    }
    if (lane == 63) wt[w] = v;
    __syncthreads();
    if (t < 16) {
        int x = wt[t];
#pragma unroll
        for (int off = 1; off < 16; off <<= 1) {
            int u = __shfl_up(x, off);
            if (t >= off) x += u;
        }
        wt2[t] = x;
    }
    __syncthreads();
    int excl = v - cnt[t] + (w ? wt2[w - 1] : 0);
    rowptr[t] = excl;
    cur[t] = excl;
    if (t == 0) rowptr[1024] = NEDGE;
    __syncthreads();
    for (int e = t; e < NEDGE; e += 1024) {
        int pos = atomicAdd(&cur[recv[e]], 1);
        csr_send[pos] = send[e];
    }
}

// ---------------------------------------------------------------------------
// MFMA GEMM (first msg + final node). A-frags direct from global.
// vstat != nullptr (with NSPLIT=2, half==1): emit per-row {mean, sumsq} of the
// bf16-rounded outputs (sender-half msg stats for edge_gather's closed-form LN).
// ---------------------------------------------------------------------------
template <int KSTEPS, int EPI, int RELU, int TRANS, int NSPLIT,
          typename TINA, typename TINB, typename TOUT>
__global__ __launch_bounds__(256) void mfma_gemm_k(
    const TINA* __restrict__ Xa, const TINB* __restrict__ Xb, int ldx,
    const bf16* __restrict__ Wt,
    const bf16* __restrict__ bias,
    const bf16* __restrict__ lng, const bf16* __restrict__ lnb,
    TOUT* __restrict__ Y, int ldy, int tshift, int ldt,
    float2* __restrict__ vstat)
{
    constexpr int K = KSTEPS * 32;
    __shared__ __align__(16) short Bs[8][64][8];
    int tid = threadIdx.x;
    int w = tid >> 6, l = tid & 63;
    int lm = l & 15, lq = l >> 4;
    int blk = blockIdx.x;
    int half = 0;
    if (NSPLIT == 2) { half = blk & 1; blk >>= 1; }
    const bf16* Wtl = Wt + (size_t)half * 128 * K;
    int colbase = half * 128;
    size_t row0 = (size_t)blk * 64;

    f32x4 acc[8];
#pragma unroll
    for (int i = 0; i < 8; i++) acc[i] = (f32x4){0.f, 0.f, 0.f, 0.f};

    for (int s = 0; s < KSTEPS; ++s) {
        int k0 = s * 32;
        __syncthreads();
        short8 a;
        if (Xb != nullptr && k0 >= 128)
            a = ld_frag(Xb + (row0 + w * 16 + lm) * (size_t)128 + (k0 - 128) + lq * 8);
        else
            a = ld_frag(Xa + (row0 + w * 16 + lm) * (size_t)ldx + k0 + lq * 8);
#pragma unroll
        for (int rr = 0; rr < 2; ++rr) {
            int idx = rr * 256 + tid;
            int nt = idx >> 6, ll = idx & 63;
            *(short8*)&Bs[nt][ll][0] =
                ld_frag(Wtl + (size_t)(nt * 16 + (ll & 15)) * K + k0 + (ll >> 4) * 8);
        }
        __syncthreads();
#pragma unroll
        for (int nt = 0; nt < 8; ++nt) {
            short8 b = *(const short8*)&Bs[nt][l][0];
            acc[nt] = __builtin_amdgcn_mfma_f32_16x16x32_bf16(a, b, acc[nt], 0, 0, 0);
        }
    }

    float v[8][4];
#pragma unroll
    for (int nt = 0; nt < 8; ++nt) {
        float bb = bias ? b2f(bias[colbase + nt * 16 + lm]) : 0.f;
#pragma unroll
        for (int r = 0; r < 4; ++r) v[nt][r] = acc[nt][r] + bb;
    }
    if constexpr (EPI == 1) {
#pragma unroll
        for (int r = 0; r < 4; ++r) {
            float s1 = 0.f, s2 = 0.f;
#pragma unroll
            for (int nt = 0; nt < 8; ++nt) { s1 += v[nt][r]; s2 += v[nt][r] * v[nt][r]; }
#pragma unroll
            for (int m = 1; m < 16; m <<= 1) { s1 += __shfl_xor(s1, m); s2 += __shfl_xor(s2, m); }
            float mu = s1 * (1.f / 128.f);
            float var = s2 * (1.f / 128.f) - mu * mu;
            float rs = rsqrtf(var + 1e-5f);
#pragma unroll
            for (int nt = 0; nt < 8; ++nt) {
                int n = nt * 16 + lm;
                v[nt][r] = (v[nt][r] - mu) * rs * b2f(lng[n]) + b2f(lnb[n]);
            }
        }
    }
    if constexpr (TRANS) {
        size_t grow = row0 + w * 16 + lq * 4;
        int bb2 = (int)(grow >> tshift);
        size_t rloc = grow & (((size_t)1 << tshift) - 1);
        bf16* YT = (bf16*)Y;
#pragma unroll
        for (int nt = 0; nt < 8; ++nt) {
            int col = colbase + nt * 16 + lm;
            ushort4 u;
            float x0 = v[nt][0], x1 = v[nt][1], x2 = v[nt][2], x3 = v[nt][3];
            if (RELU) { x0 = fmaxf(x0, 0.f); x1 = fmaxf(x1, 0.f); x2 = fmaxf(x2, 0.f); x3 = fmaxf(x3, 0.f); }
            u.x = f2bs(x0); u.y = f2bs(x1); u.z = f2bs(x2); u.w = f2bs(x3);
            *(ushort4*)(YT + ((size_t)bb2 * 128 + col) * (size_t)ldt + rloc) = u;
        }
    } else {
#pragma unroll
        for (int nt = 0; nt < 8; ++nt)
#pragma unroll
            for (int r = 0; r < 4; ++r) {
                float x = v[nt][r];
                if (RELU) x = fmaxf(x, 0.f);
                Y[(row0 + w * 16 + lq * 4 + r) * (size_t)ldy + colbase + nt * 16 + lm] = Cvt<TOUT>::to(x);
            }
        if (vstat != nullptr && half == 1) {
#pragma unroll
            for (int r = 0; r < 4; ++r) {
                float s1 = 0.f, s2 = 0.f;
#pragma unroll
                for (int nt = 0; nt < 8; ++nt) {
                    float vv = bs2f((short)f2bs(v[nt][r]));
                    s1 += vv; s2 += vv * vv;
                }
#pragma unroll
                for (int m = 1; m < 16; m <<= 1) { s1 += __shfl_xor(s1, m); s2 += __shfl_xor(s2, m); }
                if (lm == 0)
                    vstat[row0 + w * 16 + lq * 4 + r] = make_float2(s1 * (1.f / 128.f), s2);
            }
        }
    }
}

// ---------------------------------------------------------------------------
// FUSED node-GEMM+LN then msg-GEMM. v2: 32 rows/block, 256 blocks (full CU
// coverage). Waves split 2x2 over (row-half wr, col-half wc); LN and vstat
// row-sums combine across the wc wave pair via lnp[] in LDS.
// ---------------------------------------------------------------------------
__global__ __launch_bounds__(256) void node_msg_k(
    const float* __restrict__ cur, const bf16* __restrict__ inbox,
    const bf16* __restrict__ WtNode, const bf16* __restrict__ node_b,
    const bf16* __restrict__ ln2_g, const bf16* __restrict__ ln2_b,
    const bf16* __restrict__ WtMsg,
    float* __restrict__ nxt, bf16* __restrict__ PQ,
    float2* __restrict__ vstat)
{
    __shared__ __align__(16) short Bs[8][64][8];
    __shared__ __align__(16) short Act[32][136];
    __shared__ float2 lnp[4][4][4];   // [wave][lq][r] partial {s1,s2}
    int tid = threadIdx.x;
    int w = tid >> 6, l = tid & 63;
    int lm = l & 15, lq = l >> 4;
    int wr = w & 1, wc = w >> 1;
    size_t row0 = (size_t)blockIdx.x * 32;

    f32x4 acc[4];
#pragma unroll
    for (int i = 0; i < 4; i++) acc[i] = (f32x4){0.f, 0.f, 0.f, 0.f};

    // node GEMM K=256 (cur f32 | inbox bf16); this wave: rows wr*16.., cols wc*64..
    for (int s = 0; s < 8; ++s) {
        int k0 = s * 32;
        __syncthreads();
        short8 a;
        if (k0 < 128) a = ld_frag(cur + (row0 + wr * 16 + lm) * 128 + k0 + lq * 8);
        else          a = ld_frag(inbox + (row0 + wr * 16 + lm) * 128 + (k0 - 128) + lq * 8);
#pragma unroll
        for (int rr = 0; rr < 2; ++rr) {
            int idx = rr * 256 + tid;
            int nt = idx >> 6, ll = idx & 63;
            *(short8*)&Bs[nt][ll][0] =
                ld_frag(WtNode + (size_t)(nt * 16 + (ll & 15)) * 256 + k0 + (ll >> 4) * 8);
        }
        __syncthreads();
#pragma unroll
        for (int t2 = 0; t2 < 4; ++t2) {
            short8 b = *(const short8*)&Bs[wc * 4 + t2][l][0];
            acc[t2] = __builtin_amdgcn_mfma_f32_16x16x32_bf16(a, b, acc[t2], 0, 0, 0);
        }
    }
    float v[4][4];
#pragma unroll
    for (int t2 = 0; t2 < 4; ++t2) {
        float bb = b2f(node_b[wc * 64 + t2 * 16 + lm]);
#pragma unroll
        for (int r = 0; r < 4; ++r) v[t2][r] = acc[t2][r] + bb;
    }
    // LN partials (this wave's 64 cols), cross-wave combine with partner w^2
#pragma unroll
    for (int r = 0; r < 4; ++r) {
        float s1 = 0.f, s2 = 0.f;
#pragma unroll
        for (int t2 = 0; t2 < 4; ++t2) { s1 += v[t2][r]; s2 += v[t2][r] * v[t2][r]; }
#pragma unroll
        for (int m = 1; m < 16; m <<= 1) { s1 += __shfl_xor(s1, m); s2 += __shfl_xor(s2, m); }
        if (lm == 0) lnp[w][lq][r] = make_float2(s1, s2);
    }
    __syncthreads();
#pragma unroll
    for (int r = 0; r < 4; ++r) {
        float2 mine = lnp[w][lq][r], oth = lnp[w ^ 2][lq][r];
        float s1 = mine.x + oth.x, s2 = mine.y + oth.y;
        float mu = s1 * (1.f / 128.f);
        float var = s2 * (1.f / 128.f) - mu * mu;
        float rs = rsqrtf(var + 1e-5f);
#pragma unroll
        for (int t2 = 0; t2 < 4; ++t2) {
            int n = wc * 64 + t2 * 16 + lm;
            v[t2][r] = (v[t2][r] - mu) * rs * b2f(ln2_g[n]) + b2f(ln2_b[n]);
        }
    }
#pragma unroll
    for (int t2 = 0; t2 < 4; ++t2)
#pragma unroll
        for (int r = 0; r < 4; ++r) {
            nxt[(row0 + wr * 16 + lq * 4 + r) * 128 + wc * 64 + t2 * 16 + lm] = v[t2][r];
            Act[wr * 16 + lq * 4 + r][wc * 64 + t2 * 16 + lm] = (short)f2bs(v[t2][r]);
        }

    // msg GEMM for next step: two 128-col halves, A from Act
    for (int half = 0; half < 2; ++half) {
        const bf16* Wtl = WtMsg + (size_t)half * 128 * 128;
#pragma unroll
        for (int i = 0; i < 4; i++) acc[i] = (f32x4){0.f, 0.f, 0.f, 0.f};
        for (int s = 0; s < 4; ++s) {
            int k0 = s * 32;
            __syncthreads();
#pragma unroll
            for (int rr = 0; rr < 2; ++rr) {
                int idx = rr * 256 + tid;
                int nt = idx >> 6, ll = idx & 63;
                *(short8*)&Bs[nt][ll][0] =
                    ld_frag(Wtl + (size_t)(nt * 16 + (ll & 15)) * 128 + k0 + (ll >> 4) * 8);
            }
            __syncthreads();
            short8 a = *(const short8*)&Act[wr * 16 + lm][k0 + lq * 8];
#pragma unroll
            for (int t2 = 0; t2 < 4; ++t2) {
                short8 b = *(const short8*)&Bs[wc * 4 + t2][l][0];
                acc[t2] = __builtin_amdgcn_mfma_f32_16x16x32_bf16(a, b, acc[t2], 0, 0, 0);
            }
        }
#pragma unroll
        for (int t2 = 0; t2 < 4; ++t2)
#pragma unroll
            for (int r = 0; r < 4; ++r)
                PQ[(row0 + wr * 16 + lq * 4 + r) * 256 + half * 128 + wc * 64 + t2 * 16 + lm] =
                    __float2bfloat16(acc[t2][r]);
        if (half == 1) {
#pragma unroll
            for (int r = 0; r < 4; ++r) {
                float s1 = 0.f, s2 = 0.f;
#pragma unroll
                for (int t2 = 0; t2 < 4; ++t2) {
                    float vv = bs2f((short)f2bs(acc[t2][r]));
                    s1 += vv; s2 += vv * vv;
                }
#pragma unroll
                for (int m = 1; m < 16; m <<= 1) { s1 += __shfl_xor(s1, m); s2 += __shfl_xor(s2, m); }
                if (lm == 0) lnp[w][lq][r] = make_float2(s1, s2);
            }
            __syncthreads();
            if (wc == 0 && lm == 0) {
#pragma unroll
                for (int r = 0; r < 4; ++r) {
                    float2 mine = lnp[w][lq][r], oth = lnp[w + 2][lq][r];
                    vstat[row0 + wr * 16 + lq * 4 + r] =
                        make_float2((mine.x + oth.x) * (1.f / 128.f), mine.y + oth.y);
                }
            }
        }
    }
}

// ---------------------------------------------------------------------------
// FUSED per-row MLP (encoder, 3 layers). Single in-place Act tile.
// ---------------------------------------------------------------------------
template <int K0STEPS, int LAYERS, int RELU_LAST, int TRANS, typename TIN, typename TOUT>
__global__ __launch_bounds__(256) void mlp_k(
    const TIN* __restrict__ Xa, const TIN* __restrict__ Xb, int ldx,
    const bf16* __restrict__ Wt0, const bf16* __restrict__ b0,
    const bf16* __restrict__ Wt1, const bf16* __restrict__ b1,
    const bf16* __restrict__ Wt2, const bf16* __restrict__ b2,
    TOUT* __restrict__ Y, int ldy, int tshift, int ldt)
{
    constexpr int K0 = K0STEPS * 32;
    __shared__ __align__(16) short Bs[8][64][8];
    __shared__ __align__(16) short Act[64][136];
    int tid = threadIdx.x;
    int w = tid >> 6, l = tid & 63;
    int lm = l & 15, lq = l >> 4;
    size_t row0 = (size_t)blockIdx.x * 64;

    f32x4 acc[8];
#pragma unroll
    for (int i = 0; i < 8; i++) acc[i] = (f32x4){0.f, 0.f, 0.f, 0.f};

    for (int s = 0; s < K0STEPS; ++s) {
        int k0 = s * 32;
        __syncthreads();
        short8 a;
        {
            const TIN* src = Xa; int kk = k0; int ld = ldx;
            if (Xb != nullptr && k0 >= 128) { src = Xb; kk = k0 - 128; ld = 128; }
            a = ld_frag(src + (row0 + w * 16 + lm) * (size_t)ld + kk + lq * 8);
        }
#pragma unroll
        for (int rr = 0; rr < 2; ++rr) {
            int idx = rr * 256 + tid;
            int nt = idx >> 6, ll = idx & 63;
            *(short8*)&Bs[nt][ll][0] =
                ld_frag(Wt0 + (size_t)(nt * 16 + (ll & 15)) * K0 + k0 + (ll >> 4) * 8);
        }
        __syncthreads();
#pragma unroll
        for (int nt = 0; nt < 8; ++nt) {
            short8 b = *(const short8*)&Bs[nt][l][0];
            acc[nt] = __builtin_amdgcn_mfma_f32_16x16x32_bf16(a, b, acc[nt], 0, 0, 0);
        }
    }
#pragma unroll
    for (int nt = 0; nt < 8; ++nt) {
        float bb = b2f(b0[nt * 16 + lm]);
#pragma unroll
        for (int r = 0; r < 4; ++r) {
            float x = fmaxf(acc[nt][r] + bb, 0.f);
            Act[w * 16 + lq * 4 + r][nt * 16 + lm] = (short)f2bs(x);
        }
    }

    for (int L = 1; L < LAYERS; ++L) {
        const bf16* Wt = (L == 1) ? Wt1 : Wt2;
        const bf16* bias = (L == 1) ? b1 : b2;
        bool last = (L == LAYERS - 1);
#pragma unroll
        for (int i = 0; i < 8; i++) acc[i] = (f32x4){0.f, 0.f, 0.f, 0.f};
        for (int s = 0; s < 4; ++s) {
            int k0 = s * 32;
            __syncthreads();
#pragma unroll
            for (int rr = 0; rr < 2; ++rr) {
                int idx = rr * 256 + tid;
                int nt = idx >> 6, ll = idx & 63;
                *(short8*)&Bs[nt][ll][0] =
                    ld_frag(Wt + (size_t)(nt * 16 + (ll & 15)) * 128 + k0 + (ll >> 4) * 8);
            }
            __syncthreads();
            short8 a = *(const short8*)&Act[w * 16 + lm][k0 + lq * 8];
#pragma unroll
            for (int nt = 0; nt < 8; ++nt) {
                short8 b = *(const short8*)&Bs[nt][l][0];
                acc[nt] = __builtin_amdgcn_mfma_f32_16x16x32_bf16(a, b, acc[nt], 0, 0, 0);
            }
        }
        if (!last) {
            __syncthreads();
#pragma unroll
            for (int nt = 0; nt < 8; ++nt) {
                float bb = b2f(bias[nt * 16 + lm]);
#pragma unroll
                for (int r = 0; r < 4; ++r) {
                    float x = fmaxf(acc[nt][r] + bb, 0.f);
                    Act[w * 16 + lq * 4 + r][nt * 16 + lm] = (short)f2bs(x);
                }
            }
        } else {
            float v[8][4];
#pragma unroll
            for (int nt = 0; nt < 8; ++nt) {
                float bb = b2f(bias[nt * 16 + lm]);
#pragma unroll
                for (int r = 0; r < 4; ++r) {
                    float x = acc[nt][r] + bb;
                    if (RELU_LAST) x = fmaxf(x, 0.f);
                    v[nt][r] = x;
                }
            }
            if constexpr (TRANS) {
                size_t grow = row0 + w * 16 + lq * 4;
                int bb2 = (int)(grow >> tshift);
                size_t rloc = grow & (((size_t)1 << tshift) - 1);
                bf16* YT = (bf16*)Y;
#pragma unroll
                for (int nt = 0; nt < 8; ++nt) {
                    int col = nt * 16 + lm;
                    ushort4 u;
                    u.x = f2bs(v[nt][0]); u.y = f2bs(v[nt][1]);
                    u.z = f2bs(v[nt][2]); u.w = f2bs(v[nt][3]);
                    *(ushort4*)(YT + ((size_t)bb2 * 128 + col) * (size_t)ldt + rloc) = u;
                }
            } else {
#pragma unroll
                for (int nt = 0; nt < 8; ++nt)
#pragma unroll
                    for (int r = 0; r < 4; ++r)
                        Y[(row0 + w * 16 + lq * 4 + r) * (size_t)ldy + nt * 16 + lm] =
                            Cvt<TOUT>::to(v[nt][r]);
            }
        }
    }
}

// ---------------------------------------------------------------------------
// FUSED tail: qenc (3 layers) -> q in Act; dec L0 (z|q), dec L1, final 128->3.
// ---------------------------------------------------------------------------
__global__ __launch_bounds__(256) void qdec_k(
    const bf16* __restrict__ xt32,
    const bf16* __restrict__ WtQ0, const bf16* __restrict__ qb0,
    const bf16* __restrict__ WtQ1, const bf16* __restrict__ qb1,
    const bf16* __restrict__ WtQ2, const bf16* __restrict__ qb2,
    const bf16* __restrict__ z,
    const bf16* __restrict__ WtDec0, const bf16* __restrict__ db0,
    const bf16* __restrict__ WtDec1, const bf16* __restrict__ db1,
    const bf16* __restrict__ W2, const bf16* __restrict__ b2v,
    const int* __restrict__ flag, void* __restrict__ out)
{
    __shared__ __align__(16) short Bs[8][64][8];
    __shared__ __align__(16) short Act[64][136];
    __shared__ bf16 w2s[384];
    int tid = threadIdx.x;
    int w = tid >> 6, l = tid & 63;
    int lm = l & 15, lq = l >> 4;
    size_t row0 = (size_t)blockIdx.x * 64;
    for (int t = tid; t < 384; t += 256) w2s[t] = W2[t];

    f32x4 acc[8];
#pragma unroll
    for (int i = 0; i < 8; i++) acc[i] = (f32x4){0.f, 0.f, 0.f, 0.f};

    // qenc L0 (K=32)
    {
        __syncthreads();
#pragma unroll
        for (int rr = 0; rr < 2; ++rr) {
            int idx = rr * 256 + tid;
            int nt = idx >> 6, ll = idx & 63;
            *(short8*)&Bs[nt][ll][0] =
                ld_frag(WtQ0 + (size_t)(nt * 16 + (ll & 15)) * 32 + (ll >> 4) * 8);
        }
        __syncthreads();
        short8 a = ld_frag(xt32 + (row0 + w * 16 + lm) * 32 + lq * 8);
#pragma unroll
        for (int nt = 0; nt < 8; ++nt) {
            short8 b = *(const short8*)&Bs[nt][l][0];
            acc[nt] = __builtin_amdgcn_mfma_f32_16x16x32_bf16(a, b, acc[nt], 0, 0, 0);
        }
#pragma unroll
        for (int nt = 0; nt < 8; ++nt) {
            float bb = b2f(qb0[nt * 16 + lm]);
#pragma unroll
            for (int r = 0; r < 4; ++r)
                Act[w * 16 + lq * 4 + r][nt * 16 + lm] = (short)f2bs(fmaxf(acc[nt][r] + bb, 0.f));
        }
    }
    // qenc L1 (relu) and L2 (no relu) -> Act
    for (int L = 1; L < 3; ++L) {
        const bf16* Wt = (L == 1) ? WtQ1 : WtQ2;
        const bf16* bias = (L == 1) ? qb1 : qb2;
#pragma unroll
        for (int i = 0; i < 8; i++) acc[i] = (f32x4){0.f, 0.f, 0.f, 0.f};
        for (int s = 0; s < 4; ++s) {
            int k0 = s * 32;
            __syncthreads();
#pragma unroll
            for (int rr = 0; rr < 2; ++rr) {
                int idx = rr * 256 + tid;
                int nt = idx >> 6, ll = idx & 63;
                *(short8*)&Bs[nt][ll][0] =
                    ld_frag(Wt + (size_t)(nt * 16 + (ll & 15)) * 128 + k0 + (ll >> 4) * 8);
            }
            __syncthreads();
            short8 a = *(const short8*)&Act[w * 16 + lm][k0 + lq * 8];
#pragma unroll
            for (int nt = 0; nt < 8; ++nt) {
                short8 b = *(const short8*)&Bs[nt][l][0];
                acc[nt] = __builtin_amdgcn_mfma_f32_16x16x32_bf16(a, b, acc[nt], 0, 0, 0);
            }
        }
        __syncthreads();
#pragma unroll
        for (int nt = 0; nt < 8; ++nt) {
            float bb = b2f(bias[nt * 16 + lm]);
#pragma unroll
            for (int r = 0; r < 4; ++r) {
                float x = acc[nt][r] + bb;
                if (L == 1) x = fmaxf(x, 0.f);
                Act[w * 16 + lq * 4 + r][nt * 16 + lm] = (short)f2bs(x);
            }
        }
    }
    // dec L0: K=256 = z (global) | q (Act); relu -> Act
    {
#pragma unroll
        for (int i = 0; i < 8; i++) acc[i] = (f32x4){0.f, 0.f, 0.f, 0.f};
        for (int s = 0; s < 8; ++s) {
            int k0 = s * 32;
            __syncthreads();
#pragma unroll
            for (int rr = 0; rr < 2; ++rr) {
                int idx = rr * 256 + tid;
                int nt = idx >> 6, ll = idx & 63;
                *(short8*)&Bs[nt][ll][0] =
                    ld_frag(WtDec0 + (size_t)(nt * 16 + (ll & 15)) * 256 + k0 + (ll >> 4) * 8);
            }
            __syncthreads();
            short8 a;
            if (k0 < 128) a = ld_frag(z + (row0 + w * 16 + lm) * (size_t)128 + k0 + lq * 8);
            else          a = *(const short8*)&Act[w * 16 + lm][(k0 - 128) + lq * 8];
#pragma unroll
            for (int nt = 0; nt < 8; ++nt) {
                short8 b = *(const short8*)&Bs[nt][l][0];
                acc[nt] = __builtin_amdgcn_mfma_f32_16x16x32_bf16(a, b, acc[nt], 0, 0, 0);
            }
        }
        __syncthreads();
#pragma unroll
        for (int nt = 0; nt < 8; ++nt) {
            float bb = b2f(db0[nt * 16 + lm]);
#pragma unroll
            for (int r = 0; r < 4; ++r)
                Act[w * 16 + lq * 4 + r][nt * 16 + lm] = (short)f2bs(fmaxf(acc[nt][r] + bb, 0.f));
        }
    }
    // dec L1: K=128 from Act; relu -> Act
    {
#pragma unroll
        for (int i = 0; i < 8; i++) acc[i] = (f32x4){0.f, 0.f, 0.f, 0.f};
        for (int s = 0; s < 4; ++s) {
            int k0 = s * 32;
            __syncthreads();
#pragma unroll
            for (int rr = 0; rr < 2; ++rr) {
                int idx = rr * 256 + tid;
                int nt = idx >> 6, ll = idx & 63;
                *(short8*)&Bs[nt][ll][0] =
                    ld_frag(WtDec1 + (size_t)(nt * 16 + (ll & 15)) * 128 + k0 + (ll >> 4) * 8);
            }
            __syncthreads();
            short8 a = *(const short8*)&Act[w * 16 + lm][k0 + lq * 8];
#pragma unroll
            for (int nt = 0; nt < 8; ++nt) {
                short8 b = *(const short8*)&Bs[nt][l][0];
                acc[nt] = __builtin_amdgcn_mfma_f32_16x16x32_bf16(a, b, acc[nt], 0, 0, 0);
            }
        }
        __syncthreads();
#pragma unroll
        for (int nt = 0; nt < 8; ++nt) {
            float bb = b2f(db1[nt * 16 + lm]);
#pragma unroll
            for (int r = 0; r < 4; ++r)
                Act[w * 16 + lq * 4 + r][nt * 16 + lm] = (short)f2bs(fmaxf(acc[nt][r] + bb, 0.f));
        }
    }
    __syncthreads();
    // final 128 -> 3
    if (tid < 192) {
        int row = tid / 3, col = tid - (tid / 3) * 3;
        float a = b2f(b2v[col]);
        for (int k8 = 0; k8 < 16; ++k8) {
            short8 av = *(const short8*)&Act[row][k8 * 8];
#pragma unroll
            for (int j = 0; j < 8; ++j)
                a += bs2f(av[j]) * b2f(w2s[(k8 * 8 + j) * 3 + col]);
        }
        size_t o = (row0 + row) * 3 + col;
        if (*flag) ((float*)out)[o] = a;
        else       ((bf16*)out)[o] = __float2bfloat16(a);
    }
}

// ---------------------------------------------------------------------------
// fused softmax stats. v2: 4096 blocks x 4 quads (pos staged once per block).
// ---------------------------------------------------------------------------
__global__ __launch_bounds__(256) void stats2_k(const bf16* __restrict__ xcp,
                                                const bf16* __restrict__ xtp,
                                                const bf16* __restrict__ pos,
                                                float4* __restrict__ cstC4,
                                                float4* __restrict__ cstT4) {
    __shared__ float px[NNODE], py[NNODE];
    int tid = threadIdx.x;
    for (int t = tid; t < NNODE; t += 256) {
        px[t] = b2f(pos[2 * t]);
        py[t] = b2f(pos[2 * t + 1]);
    }
    __syncthreads();
    int w = tid >> 6, l = tid & 63;
#pragma unroll
    for (int it = 0; it < 4; ++it) {
        int qb = blockIdx.x + it * 4096;
        const bf16* xp = (qb < 8192) ? xcp : xtp;
        float4* st4 = (qb < 8192) ? cstC4 : cstT4;
        int pb = qb & 8191;
        int p = pb * 4 + w;
        float x = b2f(xp[2 * p]), y = b2f(xp[2 * p + 1]);
        float vals[16];
        float m = -3.4e38f;
#pragma unroll
        for (int k = 0; k < 16; k++) {
            int n = k * 64 + l;
            float dx = x - px[n], dy = y - py[n];
            float v = -(dx * dx + dy * dy);
            vals[k] = v;
            m = fmaxf(m, v);
        }
#pragma unroll
        for (int off = 32; off; off >>= 1) m = fmaxf(m, __shfl_xor(m, off));
        float s = 0.f;
#pragma unroll
        for (int k = 0; k < 16; k++) s += __expf(vals[k] - m);
#pragma unroll
        for (int off = 32; off; off >>= 1) s += __shfl_xor(s, off);
        if (l == 0) st4[p] = make_float4(x, y, m, 1.f / s);
    }
}

struct P8 { float* p[8]; };

// ---------------------------------------------------------------------------
// lat partials via MFMA. v2: cooperative LDS staging of emb chunks (dedup 4x),
// XOR-swizzled tile; up = K-step within the shared 64-col chunk.
// ---------------------------------------------------------------------------
__global__ __launch_bounds__(512, 4) void lat_mfma_k(const bf16* __restrict__ embT,
                                                     const float2* __restrict__ posf2,
                                                     const float4* __restrict__ cstC4,
                                                     P8 parts) {
    int i = blockIdx.x;
    int b = i & 7, r = i >> 3;
    int cs = r >> 4, nt = r & 15;
    int n0 = nt * 64;
    __shared__ __align__(16) float4 csh[512];
    __shared__ __align__(16) union ShU {
        short stage[2][8192];        // 2 x [128 rows][64 cols] bf16, swizzled
        float4 red[4][8][64];
    } sh;
    int tid = threadIdx.x;
    int w = tid >> 6, l = tid & 63;
    int wl = w & 3, up = w >> 2;
    int lm = l & 15, lq = l >> 4;
    int node = n0 + wl * 16 + lm;
    float2 pn = posf2[node];
    const bf16* ebase = embT + (size_t)b * (128 * LDE) + cs * 512;
    const float4* cbase = cstC4 + b * NC + cs * 512;
    csh[tid] = cbase[tid];

    int h0 = tid >> 3;
    int cb0 = (tid & 7) << 4;
    const char* g0 = (const char*)ebase + (size_t)h0 * (LDE * 2) + cb0;
    const size_t gH = (size_t)64 * (LDE * 2);
    int o0 = h0 * 128 + (cb0 ^ ((h0 & 7) << 4));   // swizzled LDS byte offset
    char* lbuf0 = (char*)&sh.stage[0][0];
    char* lbuf1 = (char*)&sh.stage[1][0];

    {
        uint4 rA = *(const uint4*)(g0);
        uint4 rB = *(const uint4*)(g0 + gH);
        *(uint4*)(lbuf0 + o0) = rA;
        *(uint4*)(lbuf0 + o0 + 64 * 128) = rB;
    }
    __syncthreads();

    f32x4 acc[8];
#pragma unroll
    for (int q = 0; q < 8; q++) acc[q] = (f32x4){0.f, 0.f, 0.f, 0.f};

    union AF { short8 s; u16 u[8]; };
    int rb = up * 64 + lq * 16;

    for (int ci = 0; ci < 8; ++ci) {
        char* cur = (ci & 1) ? lbuf1 : lbuf0;
        char* nxt = (ci & 1) ? lbuf0 : lbuf1;
        uint4 rA, rB;
        if (ci < 7) {
            const char* gs = g0 + (ci + 1) * 128;
            rA = *(const uint4*)(gs);
            rB = *(const uint4*)(gs + gH);
        }
        AF cw;
        int cidx = ci * 64 + up * 32 + lq * 8;
#pragma unroll
        for (int j = 0; j < 8; ++j) {
            float4 cc = csh[cidx + j];
            float dx = cc.x - pn.x, dy = cc.y - pn.y;
            cw.u[j] = f2bs(__expf(-(dx * dx + dy * dy) - cc.z) * cc.w);
        }
#pragma unroll
        for (int t2 = 0; t2 < 8; ++t2) {
            int h = t2 * 16 + lm;
            short8 bfr = *(const short8*)(cur + h * 128 + (rb ^ ((h & 7) << 4)));
            acc[t2] = __builtin_amdgcn_mfma_f32_16x16x32_bf16(cw.s, bfr, acc[t2], 0, 0, 0);
        }
        if (ci < 7) {
            *(uint4*)(nxt + o0) = rA;
            *(uint4*)(nxt + o0 + 64 * 128) = rB;
        }
        __syncthreads();
    }

    if (up) {
#pragma unroll
        for (int t2 = 0; t2 < 8; ++t2)
            sh.red[wl][t2][l] = make_float4(acc[t2][0], acc[t2][1], acc[t2][2], acc[t2][3]);
    }
    __syncthreads();
    if (!up) {
        float* part = parts.p[cs] + (((size_t)(b * NNODE + n0 + wl * 16 + lq * 4)) << 7) + lm;
#pragma unroll
        for (int t2 = 0; t2 < 8; ++t2) {
            float4 o = sh.red[wl][t2][l];
#pragma unroll
            for (int r2 = 0; r2 < 4; ++r2)
                part[(r2 << 7) + t2 * 16] = acc[t2][r2] + ((const float*)&o)[r2];
        }
    }
}

__global__ __launch_bounds__(256) void reduce8_k(float* __restrict__ dst, P8 parts) {
    int i = blockIdx.x * 256 + threadIdx.x;
    float4 s = ((const float4*)parts.p[0])[i];
#pragma unroll
    for (int k = 1; k < 8; ++k) {
        float4 v = ((const float4*)parts.p[k])[i];
        s.x += v.x; s.y += v.y; s.z += v.z; s.w += v.w;
    }
    ((float4*)dst)[i] = s;
}

// ---------------------------------------------------------------------------
// z via MFMA. v2: same cooperative LDS staging as lat_mfma_k.
// ---------------------------------------------------------------------------
__global__ __launch_bounds__(512, 4) void z_mfma_k(const bf16* __restrict__ latT,
                                                   const float2* __restrict__ posf2,
                                                   const float4* __restrict__ cstT4,
                                                   bf16* __restrict__ z) {
    int i = blockIdx.x;
    int b = i & 7, tt = i >> 3;
    int t0 = tt * 64;
    __shared__ __align__(8) float2 posh[1024];
    __shared__ __align__(16) union ShU {
        short stage[2][8192];
        float4 red[4][8][64];
    } sh;
    int tid = threadIdx.x;
    int w = tid >> 6, l = tid & 63;
    int wl = w & 3, up = w >> 2;
    int lm = l & 15, lq = l >> 4;
    int t = t0 + wl * 16 + lm;
    float4 qs = cstT4[b * NTT + t];
    const bf16* lbase = latT + (size_t)b * (128 * LDL);
    for (int k = tid; k < 1024; k += 512) posh[k] = posf2[k];

    int h0 = tid >> 3;
    int cb0 = (tid & 7) << 4;
    const char* g0 = (const char*)lbase + (size_t)h0 * (LDL * 2) + cb0;
    const size_t gH = (size_t)64 * (LDL * 2);
    int o0 = h0 * 128 + (cb0 ^ ((h0 & 7) << 4));
    char* lbuf0 = (char*)&sh.stage[0][0];
    char* lbuf1 = (char*)&sh.stage[1][0];

    {
        uint4 rA = *(const uint4*)(g0);
        uint4 rB = *(const uint4*)(g0 + gH);
        *(uint4*)(lbuf0 + o0) = rA;
        *(uint4*)(lbuf0 + o0 + 64 * 128) = rB;
    }
    __syncthreads();

    f32x4 acc[8];
#pragma unroll
    for (int q = 0; q < 8; q++) acc[q] = (f32x4){0.f, 0.f, 0.f, 0.f};

    union AF { short8 s; u16 u[8]; };
    int rb = up * 64 + lq * 16;

    for (int ci = 0; ci < 16; ++ci) {
        char* cur = (ci & 1) ? lbuf1 : lbuf0;
        char* nxt = (ci & 1) ? lbuf0 : lbuf1;
        uint4 rA, rB;
        if (ci < 15) {
            const char* gs = g0 + (ci + 1) * 128;
            rA = *(const uint4*)(gs);
            rB = *(const uint4*)(gs + gH);
        }
        AF cw;
        int cidx = ci * 64 + up * 32 + lq * 8;
#pragma unroll
        for (int j = 0; j < 8; ++j) {
            float2 pn = posh[cidx + j];
            float dx = qs.x - pn.x, dy = qs.y - pn.y;
            cw.u[j] = f2bs(__expf(-(dx * dx + dy * dy) - qs.z) * qs.w);
        }
#pragma unroll
        for (int t2 = 0; t2 < 8; ++t2) {
            int h = t2 * 16 + lm;
            short8 bfr = *(const short8*)(cur + h * 128 + (rb ^ ((h & 7) << 4)));
            acc[t2] = __builtin_amdgcn_mfma_f32_16x16x32_bf16(cw.s, bfr, acc[t2], 0, 0, 0);
        }
        if (ci < 15) {
            *(uint4*)(nxt + o0) = rA;
            *(uint4*)(nxt + o0 + 64 * 128) = rB;
        }
        __syncthreads();
    }

    if (up) {
#pragma unroll
        for (int t2 = 0; t2 < 8; ++t2)
            sh.red[wl][t2][l] = make_float4(acc[t2][0], acc[t2][1], acc[t2][2], acc[t2][3]);
    }
    __syncthreads();
    if (!up) {
        bf16* zp = z + (((size_t)(b * NTT + t0 + wl * 16 + lq * 4)) << 7) + lm;
#pragma unroll
        for (int t2 = 0; t2 < 8; ++t2) {
            float4 o = sh.red[wl][t2][l];
#pragma unroll
            for (int r2 = 0; r2 < 4; ++r2)
                zp[(r2 << 7) + t2 * 16] = __float2bfloat16(acc[t2][r2] + ((const float*)&o)[r2]);
        }
    }
}

// ---------------------------------------------------------------------------
// edge gather v3: closed-form per-edge LN (sender row stats precomputed);
// edge loop unrolled x4 — four interleaved single-level dot-reduce chains
// hide the 6-shuffle cross-lane latency.
// ---------------------------------------------------------------------------
__global__ __launch_bounds__(256) void edge_gather_k(const bf16* __restrict__ PQ,
                                                     const float2* __restrict__ vstat,
                                                     const int* __restrict__ rowptr,
                                                     const int* __restrict__ csr_send,
                                                     const bf16* __restrict__ mb,
                                                     const bf16* __restrict__ g1,
                                                     const bf16* __restrict__ b1,
                                                     bf16* __restrict__ inbox) {
    int tid = threadIdx.x;
    int w = tid >> 6, l = tid & 63;
    int gw = blockIdx.x * 4 + w;
    int b = gw >> 10, n = gw & 1023;
    const bf16* pqb = PQ + ((size_t)b << 18);
    const float2* vsb = vstat + b * NNODE;
    float u0 = b2f(pqb[(n << 8) + l]) + b2f(mb[l]);
    float u1 = b2f(pqb[(n << 8) + l + 64]) + b2f(mb[l + 64]);
    float g0 = b2f(g1[l]), g1v = b2f(g1[l + 64]);
    float bb0 = b2f(b1[l]), bb1 = b2f(b1[l + 64]);
    // receiver-side stats (once per node)
    float s1 = u0 + u1, s2 = u0 * u0 + u1 * u1;
#pragma unroll
    for (int off = 32; off; off >>= 1) {
        s1 += __shfl_xor(s1, off);
        s2 += __shfl_xor(s2, off);
    }
    float aN = s1 * (1.f / 128.f);
    float Su = s2;
    int beg = rowptr[n], end = rowptr[n + 1];
    float R = 0.f, M = 0.f, t0 = 0.f, t1 = 0.f;
    int i = beg;
    for (; i + 3 < end; i += 4) {
        int sA = csr_send[i], sB = csr_send[i + 1];
        int sC = csr_send[i + 2], sD = csr_send[i + 3];
        const bf16* qA = pqb + (sA << 8) + 128;
        const bf16* qB = pqb + (sB << 8) + 128;
        const bf16* qC = pqb + (sC << 8) + 128;
        const bf16* qD = pqb + (sD << 8) + 128;
        float vA0 = b2f(qA[l]), vA1 = b2f(qA[l + 64]);
        float vB0 = b2f(qB[l]), vB1 = b2f(qB[l + 64]);
        float vC0 = b2f(qC[l]), vC1 = b2f(qC[l + 64]);
        float vD0 = b2f(qD[l]), vD1 = b2f(qD[l + 64]);
        float dA = u0 * vA0 + u1 * vA1;
        float dB = u0 * vB0 + u1 * vB1;
        float dC = u0 * vC0 + u1 * vC1;
        float dD = u0 * vD0 + u1 * vD1;
#pragma unroll
        for (int off = 32; off; off >>= 1) {
            dA += __shfl_xor(dA, off);
            dB += __shfl_xor(dB, off);
            dC += __shfl_xor(dC, off);
            dD += __shfl_xor(dD, off);
        }
        float2 stA = vsb[sA], stB = vsb[sB], stC = vsb[sC], stD = vsb[sD];
        float muA = aN + stA.x;
        float rsA = rsqrtf((Su + stA.y + 2.f * dA) * (1.f / 128.f) - muA * muA + 1e-5f);
        float muB = aN + stB.x;
        float rsB = rsqrtf((Su + stB.y + 2.f * dB) * (1.f / 128.f) - muB * muB + 1e-5f);
        float muC = aN + stC.x;
        float rsC = rsqrtf((Su + stC.y + 2.f * dC) * (1.f / 128.f) - muC * muC + 1e-5f);
        float muD = aN + stD.x;
        float rsD = rsqrtf((Su + stD.y + 2.f * dD) * (1.f / 128.f) - muD * muD + 1e-5f);
        R += (rsA + rsB) + (rsC + rsD);
        M += (rsA * muA + rsB * muB) + (rsC * muC + rsD * muD);
        t0 += (rsA * vA0 + rsB * vB0) + (rsC * vC0 + rsD * vD0);
        t1 += (rsA * vA1 + rsB * vB1) + (rsC * vC1 + rsD * vD1);
    }
    for (; i < end; ++i) {
        int s = csr_send[i];
        const bf16* q = pqb + (s << 8) + 128;
        float v0 = b2f(q[l]), v1 = b2f(q[l + 64]);
        float d = u0 * v0 + u1 * v1;
#pragma unroll
        for (int off = 32; off; off >>= 1) d += __shfl_xor(d, off);
        float2 st = vsb[s];
        float mu = aN + st.x;
        float var = (Su + st.y + 2.f * d) * (1.f / 128.f) - mu * mu;
        float rs = rsqrtf(var + 1e-5f);
        R += rs;
        M += rs * mu;
        t0 += rs * v0;
        t1 += rs * v1;
    }
    float deg = (float)(end - beg);
    float a0 = g0 * (u0 * R + t0 - M) + deg * bb0;
    float a1 = g1v * (u1 * R + t1 - M) + deg * bb1;
    bf16* inb = inbox + ((size_t)b << 17) + (n << 7);
    inb[l] = __float2bfloat16(a0);
    inb[l + 64] = __float2bfloat16(a1);
}

// ---------------------------------------------------------------------------
extern "C" void kernel_launch(void* const* d_in, const int* in_sizes, int n_in,
                              void* d_out, int out_size, void* d_ws, size_t ws_size,
                              hipStream_t stream) {
    const int* senders = (const int*)d_in[30];
    const int* receivers = (const int*)d_in[31];

    char* base = (char*)d_ws;
    size_t off = 0;
    auto alloc = [&](size_t bytes) { char* p = base + off; off += (bytes + 255) & ~(size_t)255; return p; };

    int* flag = (int*)alloc(256);

    Tab tab;
    int pref = 0;
    for (int i = 0; i < 30; ++i) { tab.src[i] = d_in[i]; tab.pref[i] = pref; pref += in_sizes[i]; }
    tab.pref[30] = pref;
    bf16* arena = (bf16*)alloc((size_t)pref * 2);
    auto C = [&](int i) { return arena + tab.pref[i]; };

    float4* cstC4 = (float4*)alloc(32768 * sizeof(float4));
    float4* cstT4 = (float4*)alloc(32768 * sizeof(float4));
    float* lat0  = (float*)alloc(8192 * 128 * 4);
    float* lat1  = (float*)alloc(8192 * 128 * 4);
    float* inboxf = (float*)alloc(8192 * 128 * 4);          // lat partials only
    bf16* inbox  = (bf16*)alloc(8192 * 128 * 2);            // bf16 inbox
    bf16* T1     = (bf16*)alloc((size_t)32768 * 128 * 2);
    bf16* T2     = (bf16*)alloc((size_t)32768 * 128 * 2);
    bf16* T3     = (bf16*)alloc((size_t)32768 * 128 * 2);
    bf16* embT   = (bf16*)alloc((size_t)8 * 128 * LDE * 2);
    bf16* latT   = (bf16*)alloc((size_t)8 * 128 * LDL * 2);
    bf16* xin32  = (bf16*)alloc((size_t)32768 * 32 * 2);
    bf16* xt32   = (bf16*)alloc((size_t)32768 * 32 * 2);
    float2* posf2 = (float2*)alloc(1024 * sizeof(float2));
    float2* vstat = (float2*)alloc(8192 * sizeof(float2));
    int* rowptr  = (int*)alloc(1025 * 4);
    int* csr_send = (int*)alloc(NEDGE * 4);
    bf16* WtEnc0 = (bf16*)alloc(128 * 32 * 2);
    bf16* WtQ0   = (bf16*)alloc(128 * 32 * 2);
    bf16* WtEnc1 = (bf16*)alloc(16384 * 2);
    bf16* WtEnc2 = (bf16*)alloc(16384 * 2);
    bf16* WtQ1   = (bf16*)alloc(16384 * 2);
    bf16* WtQ2   = (bf16*)alloc(16384 * 2);
    bf16* WtDec0 = (bf16*)alloc(32768 * 2);
    bf16* WtDec1 = (bf16*)alloc(16384 * 2);
    bf16* WtMsg  = (bf16*)alloc(32768 * 2);
    bf16* WtNode = (bf16*)alloc(32768 * 2);
    bf16* PQ     = T3;   // overlay: bf16 PQ (4 MB) in T3's region; disjoint lifetime
    (void)ws_size; (void)n_in; (void)out_size;

    detect_k<<<1, 256, 0, stream>>>((const u16*)d_in[3], flag);
    ingest_k<<<(pref + 255) / 256, 256, 0, stream>>>(tab, flag, arena);

    const bf16 *xc = C(0), *yc = C(1), *xt = C(2), *pos = C(3);
    const bf16 *enc_W0 = C(4), *enc_b0 = C(5), *enc_W1 = C(6), *enc_b1 = C(7), *enc_W2 = C(8), *enc_b2 = C(9);
    const bf16 *qenc_W0 = C(10), *qenc_b0 = C(11), *qenc_W1 = C(12), *qenc_b1 = C(13), *qenc_W2 = C(14), *qenc_b2 = C(15);
    const bf16 *dec_W0 = C(16), *dec_b0 = C(17), *dec_W1 = C(18), *dec_b1 = C(19), *dec_W2 = C(20), *dec_b2 = C(21);
    const bf16 *msg_W = C(22), *msg_b = C(23), *ln1_g = C(24), *ln1_b = C(25);
    const bf16 *node_W = C(26), *node_b = C(27), *ln2_g = C(28), *ln2_b = C(29);

    TT tt;
    const bf16* s11[11] = { enc_W1, enc_W2, qenc_W1, qenc_W2, dec_W1, dec_W0, msg_W, msg_W + 16384, node_W, enc_W0, qenc_W0 };
    bf16* d11[11]       = { WtEnc1, WtEnc2, WtQ1,    WtQ2,    WtDec1, WtDec0, WtMsg, WtMsg + 16384, WtNode, WtEnc0, WtQ0   };
    int sk11[11] = { 128, 128, 128, 128, 128, 256, 128, 128, 256, 5, 2 };
    int dk11[11] = { 128, 128, 128, 128, 128, 256, 128, 128, 256, 32, 32 };
    int tp = 0;
    for (int i = 0; i < 11; ++i) {
        tt.src[i] = s11[i]; tt.dst[i] = d11[i]; tt.srcK[i] = sk11[i]; tt.dK[i] = dk11[i];
        tt.pref[i] = tp; tp += dk11[i] * 128;
    }
    tt.pref[11] = tp;

    prep_trans_k<<<128 + (tp + 255) / 256, 256, 0, stream>>>(tt, xc, yc, xt, pos, xin32, xt32, posf2);
    build_csr_k<<<1, 1024, 0, stream>>>(receivers, senders, rowptr, csr_send);

    // encoder (fused 3-layer MLP): xin32 -> embT (transposed, padded rows)
    mlp_k<1, 3, 0, 1, bf16, bf16><<<512, 256, 0, stream>>>(
        xin32, nullptr, 32, WtEnc0, enc_b0, WtEnc1, enc_b1, WtEnc2, enc_b2, embT, 128, 12, LDE);

    stats2_k<<<4096, 256, 0, stream>>>(xc, xt, pos, cstC4, cstT4);

    P8 parts;
    parts.p[0] = lat1;
    parts.p[1] = inboxf;
    parts.p[2] = (float*)T1;
    parts.p[3] = (float*)T1 + 1048576;
    parts.p[4] = (float*)T2;
    parts.p[5] = (float*)T2 + 1048576;
    parts.p[6] = (float*)T3;
    parts.p[7] = (float*)T3 + 1048576;
    lat_mfma_k<<<1024, 512, 0, stream>>>(embT, posf2, cstC4, parts);
    reduce8_k<<<1024, 256, 0, stream>>>(lat0, parts);

    // 4-step recurrence, node+msg fused; PQ/inbox in bf16; vstat for closed-form LN
    mfma_gemm_k<4, 0, 0, 0, 2, float, float, bf16><<<256, 256, 0, stream>>>(lat0, nullptr, 128, WtMsg, nullptr, nullptr, nullptr, PQ, 256, 0, 0, vstat);
    edge_gather_k<<<2048, 256, 0, stream>>>(PQ, vstat, rowptr, csr_send, msg_b, ln1_g, ln1_b, inbox);
    node_msg_k<<<256, 256, 0, stream>>>(lat0, inbox, WtNode, node_b, ln2_g, ln2_b, WtMsg, lat1, PQ, vstat);
    edge_gather_k<<<2048, 256, 0, stream>>>(PQ, vstat, rowptr, csr_send, msg_b, ln1_g, ln1_b, inbox);
    node_msg_k<<<256, 256, 0, stream>>>(lat1, inbox, WtNode, node_b, ln2_g, ln2_b, WtMsg, lat0, PQ, vstat);
    edge_gather_k<<<2048, 256, 0, stream>>>(PQ, vstat, rowptr, csr_send, msg_b, ln1_g, ln1_b, inbox);
    node_msg_k<<<256, 256, 0, stream>>>(lat0, inbox, WtNode, node_b, ln2_g, ln2_b, WtMsg, lat1, PQ, vstat);
    edge_gather_k<<<2048, 256, 0, stream>>>(PQ, vstat, rowptr, csr_send, msg_b, ln1_g, ln1_b, inbox);
    mfma_gemm_k<8, 1, 0, 1, 1, float, bf16, bf16><<<128, 256, 0, stream>>>(lat1, inbox, 128, WtNode, node_b, ln2_g, ln2_b, latT, 128, 10, LDL, nullptr);

    // z -> T2 (bf16)
    z_mfma_k<<<512, 512, 0, stream>>>(latT, posf2, cstT4, T2);

    // fused tail: qenc(xt32) + dec(z|q) + final -> out
    qdec_k<<<512, 256, 0, stream>>>(xt32,
                                    WtQ0, qenc_b0, WtQ1, qenc_b1, WtQ2, qenc_b2,
                                    T2,
                                    WtDec0, dec_b0, WtDec1, dec_b1,
                                    dec_W2, dec_b2, flag, d_out);
}

// Round 14
// 389.125 us; speedup vs baseline: 1.9073x; 1.0144x over previous
//
#include <hip/hip_runtime.h>
#include <hip/hip_bf16.h>
#include <string.h>

#define BB 8
#define NC 4096
#define NTT 4096
#define NNODE 1024
#define NEDGE 16384
#define LDE 4128   // embT row-dim padded (+64B) to break 8KB power-of-2 stride
#define LDL 1056   // latT row-dim padded (+64B) to break 2KB power-of-2 stride

typedef __hip_bfloat16 bf16;
typedef unsigned short u16;
typedef __attribute__((ext_vector_type(8))) short short8;
typedef __attribute__((ext_vector_type(4))) float f32x4;

__device__ __forceinline__ float b2f(bf16 x) { return __bfloat162float(x); }
__device__ __forceinline__ float bs2f(short s) { return __uint_as_float(((unsigned)(unsigned short)s) << 16); }

template <typename T> struct Cvt;
template <> struct Cvt<float> { static __device__ __forceinline__ float to(float v) { return v; } };
template <> struct Cvt<bf16>  { static __device__ __forceinline__ bf16  to(float v) { return __float2bfloat16(v); } };

__device__ __forceinline__ unsigned short f2bs(float x) {
    unsigned u = __float_as_uint(x);
    return (unsigned short)((u + 0x7FFFu + ((u >> 16) & 1u)) >> 16);
}

__device__ __forceinline__ short8 ld_frag(const bf16* g) {
    union { uint4 u4; short8 s8; } cv;
    cv.u4 = *(const uint4*)g;
    return cv.s8;
}
__device__ __forceinline__ short8 ld_frag(const float* g) {
    float4 f0 = *(const float4*)g;
    float4 f1 = *(const float4*)(g + 4);
    short8 r;
    r[0] = (short)f2bs(f0.x); r[1] = (short)f2bs(f0.y);
    r[2] = (short)f2bs(f0.z); r[3] = (short)f2bs(f0.w);
    r[4] = (short)f2bs(f1.x); r[5] = (short)f2bs(f1.y);
    r[6] = (short)f2bs(f1.z); r[7] = (short)f2bs(f1.w);
    return r;
}

// ---------------------------------------------------------------------------
__global__ void detect_k(const u16* __restrict__ posu, int* __restrict__ flag) {
    __shared__ int cnt;
    if (threadIdx.x == 0) cnt = 0;
    __syncthreads();
    int wild = 0;
    for (int i = threadIdx.x; i < 1024; i += 256) {
        u16 u = posu[2 * i];
        int ex = (u >> 7) & 0xFF;
        if (ex == 0 || ex == 0xFF || ex > 137 || ex < 107) wild++;
    }
    atomicAdd(&cnt, wild);
    __syncthreads();
    if (threadIdx.x == 0) *flag = (cnt > 50) ? 1 : 0;
}

// ---------------------------------------------------------------------------
struct Tab { const void* src[30]; int pref[31]; };

__global__ __launch_bounds__(256) void ingest_k(Tab tab, const int* __restrict__ flag,
                                                bf16* __restrict__ dst) {
    int idx = blockIdx.x * 256 + threadIdx.x;
    if (idx >= tab.pref[30]) return;
    int t = 0;
    while (tab.pref[t + 1] <= idx) t++;
    int e = idx - tab.pref[t];
    float v;
    if (*flag) v = ((const float*)tab.src[t])[e];
    else       v = b2f(((const bf16*)tab.src[t])[e]);
    dst[idx] = __float2bfloat16(v);
}

// ---------------------------------------------------------------------------
// fused prep (blocks 0..127) + zero-padding weight transpose (blocks 128..)
// ---------------------------------------------------------------------------
struct TT { const bf16* src[11]; bf16* dst[11]; int srcK[11]; int dK[11]; int pref[12]; };

__global__ __launch_bounds__(256) void prep_trans_k(
    TT tt,
    const bf16* __restrict__ xc, const bf16* __restrict__ yc,
    const bf16* __restrict__ xt,
    const bf16* __restrict__ pos,
    bf16* __restrict__ xin32, bf16* __restrict__ xt32,
    float2* __restrict__ posf2) {
    if (blockIdx.x < 128) {
        int row = blockIdx.x * 256 + threadIdx.x;
        bf16 z = __float2bfloat16(0.f);
        bf16* xr = xin32 + row * 32;
        xr[0] = xc[row * 2 + 0];
        xr[1] = xc[row * 2 + 1];
        xr[2] = yc[row * 3 + 0];
        xr[3] = yc[row * 3 + 1];
        xr[4] = yc[row * 3 + 2];
#pragma unroll
        for (int k = 5; k < 32; ++k) xr[k] = z;
        bf16* tr = xt32 + row * 32;
        tr[0] = xt[row * 2 + 0];
        tr[1] = xt[row * 2 + 1];
#pragma unroll
        for (int k = 2; k < 32; ++k) tr[k] = z;
        if (row < NNODE) posf2[row] = make_float2(b2f(pos[2 * row]), b2f(pos[2 * row + 1]));
        return;
    }
    int idx = (blockIdx.x - 128) * 256 + threadIdx.x;
    if (idx >= tt.pref[11]) return;
    int t = 0;
    while (tt.pref[t + 1] <= idx) t++;
    int e = idx - tt.pref[t];
    int k = e >> 7, n = e & 127;
    bf16 v = (k < tt.srcK[t]) ? tt.src[t][k * 128 + n] : __float2bfloat16(0.f);
    tt.dst[t][n * tt.dK[t] + k] = v;
}

// ---------------------------------------------------------------------------
__global__ __launch_bounds__(1024) void build_csr_k(const int* __restrict__ recv,
                                                    const int* __restrict__ send,
                                                    int* __restrict__ rowptr,
                                                    int* __restrict__ csr_send) {
    __shared__ int cnt[1024];
    __shared__ int wt[16], wt2[16];
    __shared__ int cur[1024];
    int t = threadIdx.x;
    cnt[t] = 0;
    __syncthreads();
    for (int e = t; e < NEDGE; e += 1024) atomicAdd(&cnt[recv[e]], 1);
    __syncthreads();
    int v = cnt[t];
    int lane = t & 63, w = t >> 6;
#pragma unroll
    for (int off = 1; off < 64; off <<= 1) {
        int u = __shfl_up(v, off);
        if (lane >= off) v += u;
    }
    if (lane == 63) wt[w] = v;
    __syncthreads();
    if (t < 16) {
        int x = wt[t];
#pragma unroll
        for (int off = 1; off < 16; off <<= 1) {
            int u = __shfl_up(x, off);
            if (t >= off) x += u;
        }
        wt2[t] = x;
    }
    __syncthreads();
    int excl = v - cnt[t] + (w ? wt2[w - 1] : 0);
    rowptr[t] = excl;
    cur[t] = excl;
    if (t == 0) rowptr[1024] = NEDGE;
    __syncthreads();
    for (int e = t; e < NEDGE; e += 1024) {
        int pos = atomicAdd(&cur[recv[e]], 1);
        csr_send[pos] = send[e];
    }
}

struct P8 { float* p[8]; };

// ---------------------------------------------------------------------------
// MFMA GEMM (final node). A-frags direct from global.
// ---------------------------------------------------------------------------
template <int KSTEPS, int EPI, int RELU, int TRANS, int NSPLIT,
          typename TINA, typename TINB, typename TOUT>
__global__ __launch_bounds__(256) void mfma_gemm_k(
    const TINA* __restrict__ Xa, const TINB* __restrict__ Xb, int ldx,
    const bf16* __restrict__ Wt,
    const bf16* __restrict__ bias,
    const bf16* __restrict__ lng, const bf16* __restrict__ lnb,
    TOUT* __restrict__ Y, int ldy, int tshift, int ldt,
    float2* __restrict__ vstat)
{
    constexpr int K = KSTEPS * 32;
    __shared__ __align__(16) short Bs[8][64][8];
    int tid = threadIdx.x;
    int w = tid >> 6, l = tid & 63;
    int lm = l & 15, lq = l >> 4;
    int blk = blockIdx.x;
    int half = 0;
    if (NSPLIT == 2) { half = blk & 1; blk >>= 1; }
    const bf16* Wtl = Wt + (size_t)half * 128 * K;
    int colbase = half * 128;
    size_t row0 = (size_t)blk * 64;

    f32x4 acc[8];
#pragma unroll
    for (int i = 0; i < 8; i++) acc[i] = (f32x4){0.f, 0.f, 0.f, 0.f};

    for (int s = 0; s < KSTEPS; ++s) {
        int k0 = s * 32;
        __syncthreads();
        short8 a;
        if (Xb != nullptr && k0 >= 128)
            a = ld_frag(Xb + (row0 + w * 16 + lm) * (size_t)128 + (k0 - 128) + lq * 8);
        else
            a = ld_frag(Xa + (row0 + w * 16 + lm) * (size_t)ldx + k0 + lq * 8);
#pragma unroll
        for (int rr = 0; rr < 2; ++rr) {
            int idx = rr * 256 + tid;
            int nt = idx >> 6, ll = idx & 63;
            *(short8*)&Bs[nt][ll][0] =
                ld_frag(Wtl + (size_t)(nt * 16 + (ll & 15)) * K + k0 + (ll >> 4) * 8);
        }
        __syncthreads();
#pragma unroll
        for (int nt = 0; nt < 8; ++nt) {
            short8 b = *(const short8*)&Bs[nt][l][0];
            acc[nt] = __builtin_amdgcn_mfma_f32_16x16x32_bf16(a, b, acc[nt], 0, 0, 0);
        }
    }

    float v[8][4];
#pragma unroll
    for (int nt = 0; nt < 8; ++nt) {
        float bb = bias ? b2f(bias[colbase + nt * 16 + lm]) : 0.f;
#pragma unroll
        for (int r = 0; r < 4; ++r) v[nt][r] = acc[nt][r] + bb;
    }
    if constexpr (EPI == 1) {
#pragma unroll
        for (int r = 0; r < 4; ++r) {
            float s1 = 0.f, s2 = 0.f;
#pragma unroll
            for (int nt = 0; nt < 8; ++nt) { s1 += v[nt][r]; s2 += v[nt][r] * v[nt][r]; }
#pragma unroll
            for (int m = 1; m < 16; m <<= 1) { s1 += __shfl_xor(s1, m); s2 += __shfl_xor(s2, m); }
            float mu = s1 * (1.f / 128.f);
            float var = s2 * (1.f / 128.f) - mu * mu;
            float rs = rsqrtf(var + 1e-5f);
#pragma unroll
            for (int nt = 0; nt < 8; ++nt) {
                int n = nt * 16 + lm;
                v[nt][r] = (v[nt][r] - mu) * rs * b2f(lng[n]) + b2f(lnb[n]);
            }
        }
    }
    if constexpr (TRANS) {
        size_t grow = row0 + w * 16 + lq * 4;
        int bb2 = (int)(grow >> tshift);
        size_t rloc = grow & (((size_t)1 << tshift) - 1);
        bf16* YT = (bf16*)Y;
#pragma unroll
        for (int nt = 0; nt < 8; ++nt) {
            int col = colbase + nt * 16 + lm;
            ushort4 u;
            float x0 = v[nt][0], x1 = v[nt][1], x2 = v[nt][2], x3 = v[nt][3];
            if (RELU) { x0 = fmaxf(x0, 0.f); x1 = fmaxf(x1, 0.f); x2 = fmaxf(x2, 0.f); x3 = fmaxf(x3, 0.f); }
            u.x = f2bs(x0); u.y = f2bs(x1); u.z = f2bs(x2); u.w = f2bs(x3);
            *(ushort4*)(YT + ((size_t)bb2 * 128 + col) * (size_t)ldt + rloc) = u;
        }
    } else {
#pragma unroll
        for (int nt = 0; nt < 8; ++nt)
#pragma unroll
            for (int r = 0; r < 4; ++r) {
                float x = v[nt][r];
                if (RELU) x = fmaxf(x, 0.f);
                Y[(row0 + w * 16 + lq * 4 + r) * (size_t)ldy + colbase + nt * 16 + lm] = Cvt<TOUT>::to(x);
            }
        if (vstat != nullptr && half == 1) {
#pragma unroll
            for (int r = 0; r < 4; ++r) {
                float s1 = 0.f, s2 = 0.f;
#pragma unroll
                for (int nt = 0; nt < 8; ++nt) {
                    float vv = bs2f((short)f2bs(v[nt][r]));
                    s1 += vv; s2 += vv * vv;
                }
#pragma unroll
                for (int m = 1; m < 16; m <<= 1) { s1 += __shfl_xor(s1, m); s2 += __shfl_xor(s2, m); }
                if (lm == 0)
                    vstat[row0 + w * 16 + lq * 4 + r] = make_float2(s1 * (1.f / 128.f), s2);
            }
        }
    }
}

// ---------------------------------------------------------------------------
// FUSED reduce8 + msg0 GEMM: sum 8 lat partials -> lat0 (f32) + Act (bf16),
// then msg GEMM (two 128-col halves) from Act -> PQ + vstat. 32 rows/block,
// 256 blocks (full CU coverage). Mirrors node_msg_k's measured msg phase.
// ---------------------------------------------------------------------------
__global__ __launch_bounds__(256) void red_msg_k(
    P8 parts, float* __restrict__ lat0,
    const bf16* __restrict__ WtMsg,
    bf16* __restrict__ PQ, float2* __restrict__ vstat)
{
    __shared__ __align__(16) short Bs[8][64][8];
    __shared__ __align__(16) short Act[32][136];
    __shared__ float2 lnp[4][4][4];
    int tid = threadIdx.x;
    int w = tid >> 6, l = tid & 63;
    int lm = l & 15, lq = l >> 4;
    int wr = w & 1, wc = w >> 1;
    size_t row0 = (size_t)blockIdx.x * 32;

    // reduce 8 partials -> lat0 + Act (same summation order as reduce8_k)
    size_t base = row0 * 32;   // float4 index: row0*128/4
#pragma unroll
    for (int it = 0; it < 4; ++it) {
        size_t i = base + it * 256 + tid;
        float4 s = ((const float4*)parts.p[0])[i];
#pragma unroll
        for (int k = 1; k < 8; ++k) {
            float4 v = ((const float4*)parts.p[k])[i];
            s.x += v.x; s.y += v.y; s.z += v.z; s.w += v.w;
        }
        ((float4*)lat0)[i] = s;
        int li = it * 256 + tid;        // local float4 within 32x128 tile
        int r = li >> 5;                // 32 float4 per row
        int c4 = (li & 31) << 2;
        short* ap = &Act[r][c4];
        ap[0] = (short)f2bs(s.x); ap[1] = (short)f2bs(s.y);
        ap[2] = (short)f2bs(s.z); ap[3] = (short)f2bs(s.w);
    }
    __syncthreads();

    f32x4 acc[4];
    for (int half = 0; half < 2; ++half) {
        const bf16* Wtl = WtMsg + (size_t)half * 128 * 128;
#pragma unroll
        for (int i = 0; i < 4; i++) acc[i] = (f32x4){0.f, 0.f, 0.f, 0.f};
        for (int s = 0; s < 4; ++s) {
            int k0 = s * 32;
            __syncthreads();
#pragma unroll
            for (int rr = 0; rr < 2; ++rr) {
                int idx = rr * 256 + tid;
                int nt = idx >> 6, ll = idx & 63;
                *(short8*)&Bs[nt][ll][0] =
                    ld_frag(Wtl + (size_t)(nt * 16 + (ll & 15)) * 128 + k0 + (ll >> 4) * 8);
            }
            __syncthreads();
            short8 a = *(const short8*)&Act[wr * 16 + lm][k0 + lq * 8];
#pragma unroll
            for (int t2 = 0; t2 < 4; ++t2) {
                short8 b = *(const short8*)&Bs[wc * 4 + t2][l][0];
                acc[t2] = __builtin_amdgcn_mfma_f32_16x16x32_bf16(a, b, acc[t2], 0, 0, 0);
            }
        }
#pragma unroll
        for (int t2 = 0; t2 < 4; ++t2)
#pragma unroll
            for (int r = 0; r < 4; ++r)
                PQ[(row0 + wr * 16 + lq * 4 + r) * 256 + half * 128 + wc * 64 + t2 * 16 + lm] =
                    __float2bfloat16(acc[t2][r]);
        if (half == 1) {
#pragma unroll
            for (int r = 0; r < 4; ++r) {
                float s1 = 0.f, s2 = 0.f;
#pragma unroll
                for (int t2 = 0; t2 < 4; ++t2) {
                    float vv = bs2f((short)f2bs(acc[t2][r]));
                    s1 += vv; s2 += vv * vv;
                }
#pragma unroll
                for (int m = 1; m < 16; m <<= 1) { s1 += __shfl_xor(s1, m); s2 += __shfl_xor(s2, m); }
                if (lm == 0) lnp[w][lq][r] = make_float2(s1, s2);
            }
            __syncthreads();
            if (wc == 0 && lm == 0) {
#pragma unroll
                for (int r = 0; r < 4; ++r) {
                    float2 mine = lnp[w][lq][r], oth = lnp[w + 2][lq][r];
                    vstat[row0 + wr * 16 + lq * 4 + r] =
                        make_float2((mine.x + oth.x) * (1.f / 128.f), mine.y + oth.y);
                }
            }
        }
    }
}

// ---------------------------------------------------------------------------
// FUSED node-GEMM+LN then msg-GEMM. 32 rows/block, 256 blocks. Waves split
// 2x2 over (row-half wr, col-half wc); LN/vstat combine via lnp[] in LDS.
// ---------------------------------------------------------------------------
__global__ __launch_bounds__(256) void node_msg_k(
    const float* __restrict__ cur, const bf16* __restrict__ inbox,
    const bf16* __restrict__ WtNode, const bf16* __restrict__ node_b,
    const bf16* __restrict__ ln2_g, const bf16* __restrict__ ln2_b,
    const bf16* __restrict__ WtMsg,
    float* __restrict__ nxt, bf16* __restrict__ PQ,
    float2* __restrict__ vstat)
{
    __shared__ __align__(16) short Bs[8][64][8];
    __shared__ __align__(16) short Act[32][136];
    __shared__ float2 lnp[4][4][4];   // [wave][lq][r] partial {s1,s2}
    int tid = threadIdx.x;
    int w = tid >> 6, l = tid & 63;
    int lm = l & 15, lq = l >> 4;
    int wr = w & 1, wc = w >> 1;
    size_t row0 = (size_t)blockIdx.x * 32;

    f32x4 acc[4];
#pragma unroll
    for (int i = 0; i < 4; i++) acc[i] = (f32x4){0.f, 0.f, 0.f, 0.f};

    // node GEMM K=256 (cur f32 | inbox bf16); this wave: rows wr*16.., cols wc*64..
    for (int s = 0; s < 8; ++s) {
        int k0 = s * 32;
        __syncthreads();
        short8 a;
        if (k0 < 128) a = ld_frag(cur + (row0 + wr * 16 + lm) * 128 + k0 + lq * 8);
        else          a = ld_frag(inbox + (row0 + wr * 16 + lm) * 128 + (k0 - 128) + lq * 8);
#pragma unroll
        for (int rr = 0; rr < 2; ++rr) {
            int idx = rr * 256 + tid;
            int nt = idx >> 6, ll = idx & 63;
            *(short8*)&Bs[nt][ll][0] =
                ld_frag(WtNode + (size_t)(nt * 16 + (ll & 15)) * 256 + k0 + (ll >> 4) * 8);
        }
        __syncthreads();
#pragma unroll
        for (int t2 = 0; t2 < 4; ++t2) {
            short8 b = *(const short8*)&Bs[wc * 4 + t2][l][0];
            acc[t2] = __builtin_amdgcn_mfma_f32_16x16x32_bf16(a, b, acc[t2], 0, 0, 0);
        }
    }
    float v[4][4];
#pragma unroll
    for (int t2 = 0; t2 < 4; ++t2) {
        float bb = b2f(node_b[wc * 64 + t2 * 16 + lm]);
#pragma unroll
        for (int r = 0; r < 4; ++r) v[t2][r] = acc[t2][r] + bb;
    }
    // LN partials (this wave's 64 cols), cross-wave combine with partner w^2
#pragma unroll
    for (int r = 0; r < 4; ++r) {
        float s1 = 0.f, s2 = 0.f;
#pragma unroll
        for (int t2 = 0; t2 < 4; ++t2) { s1 += v[t2][r]; s2 += v[t2][r] * v[t2][r]; }
#pragma unroll
        for (int m = 1; m < 16; m <<= 1) { s1 += __shfl_xor(s1, m); s2 += __shfl_xor(s2, m); }
        if (lm == 0) lnp[w][lq][r] = make_float2(s1, s2);
    }
    __syncthreads();
#pragma unroll
    for (int r = 0; r < 4; ++r) {
        float2 mine = lnp[w][lq][r], oth = lnp[w ^ 2][lq][r];
        float s1 = mine.x + oth.x, s2 = mine.y + oth.y;
        float mu = s1 * (1.f / 128.f);
        float var = s2 * (1.f / 128.f) - mu * mu;
        float rs = rsqrtf(var + 1e-5f);
#pragma unroll
        for (int t2 = 0; t2 < 4; ++t2) {
            int n = wc * 64 + t2 * 16 + lm;
            v[t2][r] = (v[t2][r] - mu) * rs * b2f(ln2_g[n]) + b2f(ln2_b[n]);
        }
    }
#pragma unroll
    for (int t2 = 0; t2 < 4; ++t2)
#pragma unroll
        for (int r = 0; r < 4; ++r) {
            nxt[(row0 + wr * 16 + lq * 4 + r) * 128 + wc * 64 + t2 * 16 + lm] = v[t2][r];
            Act[wr * 16 + lq * 4 + r][wc * 64 + t2 * 16 + lm] = (short)f2bs(v[t2][r]);
        }

    // msg GEMM for next step: two 128-col halves, A from Act
    for (int half = 0; half < 2; ++half) {
        const bf16* Wtl = WtMsg + (size_t)half * 128 * 128;
#pragma unroll
        for (int i = 0; i < 4; i++) acc[i] = (f32x4){0.f, 0.f, 0.f, 0.f};
        for (int s = 0; s < 4; ++s) {
            int k0 = s * 32;
            __syncthreads();
#pragma unroll
            for (int rr = 0; rr < 2; ++rr) {
                int idx = rr * 256 + tid;
                int nt = idx >> 6, ll = idx & 63;
                *(short8*)&Bs[nt][ll][0] =
                    ld_frag(Wtl + (size_t)(nt * 16 + (ll & 15)) * 128 + k0 + (ll >> 4) * 8);
            }
            __syncthreads();
            short8 a = *(const short8*)&Act[wr * 16 + lm][k0 + lq * 8];
#pragma unroll
            for (int t2 = 0; t2 < 4; ++t2) {
                short8 b = *(const short8*)&Bs[wc * 4 + t2][l][0];
                acc[t2] = __builtin_amdgcn_mfma_f32_16x16x32_bf16(a, b, acc[t2], 0, 0, 0);
            }
        }
#pragma unroll
        for (int t2 = 0; t2 < 4; ++t2)
#pragma unroll
            for (int r = 0; r < 4; ++r)
                PQ[(row0 + wr * 16 + lq * 4 + r) * 256 + half * 128 + wc * 64 + t2 * 16 + lm] =
                    __float2bfloat16(acc[t2][r]);
        if (half == 1) {
#pragma unroll
            for (int r = 0; r < 4; ++r) {
                float s1 = 0.f, s2 = 0.f;
#pragma unroll
                for (int t2 = 0; t2 < 4; ++t2) {
                    float vv = bs2f((short)f2bs(acc[t2][r]));
                    s1 += vv; s2 += vv * vv;
                }
#pragma unroll
                for (int m = 1; m < 16; m <<= 1) { s1 += __shfl_xor(s1, m); s2 += __shfl_xor(s2, m); }
                if (lm == 0) lnp[w][lq][r] = make_float2(s1, s2);
            }
            __syncthreads();
            if (wc == 0 && lm == 0) {
#pragma unroll
                for (int r = 0; r < 4; ++r) {
                    float2 mine = lnp[w][lq][r], oth = lnp[w + 2][lq][r];
                    vstat[row0 + wr * 16 + lq * 4 + r] =
                        make_float2((mine.x + oth.x) * (1.f / 128.f), mine.y + oth.y);
                }
            }
        }
    }
}

// ---------------------------------------------------------------------------
// FUSED per-row MLP (encoder, 3 layers). Single in-place Act tile.
// ---------------------------------------------------------------------------
template <int K0STEPS, int LAYERS, int RELU_LAST, int TRANS, typename TIN, typename TOUT>
__global__ __launch_bounds__(256) void mlp_k(
    const TIN* __restrict__ Xa, const TIN* __restrict__ Xb, int ldx,
    const bf16* __restrict__ Wt0, const bf16* __restrict__ b0,
    const bf16* __restrict__ Wt1, const bf16* __restrict__ b1,
    const bf16* __restrict__ Wt2, const bf16* __restrict__ b2,
    TOUT* __restrict__ Y, int ldy, int tshift, int ldt)
{
    constexpr int K0 = K0STEPS * 32;
    __shared__ __align__(16) short Bs[8][64][8];
    __shared__ __align__(16) short Act[64][136];
    int tid = threadIdx.x;
    int w = tid >> 6, l = tid & 63;
    int lm = l & 15, lq = l >> 4;
    size_t row0 = (size_t)blockIdx.x * 64;

    f32x4 acc[8];
#pragma unroll
    for (int i = 0; i < 8; i++) acc[i] = (f32x4){0.f, 0.f, 0.f, 0.f};

    for (int s = 0; s < K0STEPS; ++s) {
        int k0 = s * 32;
        __syncthreads();
        short8 a;
        {
            const TIN* src = Xa; int kk = k0; int ld = ldx;
            if (Xb != nullptr && k0 >= 128) { src = Xb; kk = k0 - 128; ld = 128; }
            a = ld_frag(src + (row0 + w * 16 + lm) * (size_t)ld + kk + lq * 8);
        }
#pragma unroll
        for (int rr = 0; rr < 2; ++rr) {
            int idx = rr * 256 + tid;
            int nt = idx >> 6, ll = idx & 63;
            *(short8*)&Bs[nt][ll][0] =
                ld_frag(Wt0 + (size_t)(nt * 16 + (ll & 15)) * K0 + k0 + (ll >> 4) * 8);
        }
        __syncthreads();
#pragma unroll
        for (int nt = 0; nt < 8; ++nt) {
            short8 b = *(const short8*)&Bs[nt][l][0];
            acc[nt] = __builtin_amdgcn_mfma_f32_16x16x32_bf16(a, b, acc[nt], 0, 0, 0);
        }
    }
#pragma unroll
    for (int nt = 0; nt < 8; ++nt) {
        float bb = b2f(b0[nt * 16 + lm]);
#pragma unroll
        for (int r = 0; r < 4; ++r) {
            float x = fmaxf(acc[nt][r] + bb, 0.f);
            Act[w * 16 + lq * 4 + r][nt * 16 + lm] = (short)f2bs(x);
        }
    }

    for (int L = 1; L < LAYERS; ++L) {
        const bf16* Wt = (L == 1) ? Wt1 : Wt2;
        const bf16* bias = (L == 1) ? b1 : b2;
        bool last = (L == LAYERS - 1);
#pragma unroll
        for (int i = 0; i < 8; i++) acc[i] = (f32x4){0.f, 0.f, 0.f, 0.f};
        for (int s = 0; s < 4; ++s) {
            int k0 = s * 32;
            __syncthreads();
#pragma unroll
            for (int rr = 0; rr < 2; ++rr) {
                int idx = rr * 256 + tid;
                int nt = idx >> 6, ll = idx & 63;
                *(short8*)&Bs[nt][ll][0] =
                    ld_frag(Wt + (size_t)(nt * 16 + (ll & 15)) * 128 + k0 + (ll >> 4) * 8);
            }
            __syncthreads();
            short8 a = *(const short8*)&Act[w * 16 + lm][k0 + lq * 8];
#pragma unroll
            for (int nt = 0; nt < 8; ++nt) {
                short8 b = *(const short8*)&Bs[nt][l][0];
                acc[nt] = __builtin_amdgcn_mfma_f32_16x16x32_bf16(a, b, acc[nt], 0, 0, 0);
            }
        }
        if (!last) {
            __syncthreads();
#pragma unroll
            for (int nt = 0; nt < 8; ++nt) {
                float bb = b2f(bias[nt * 16 + lm]);
#pragma unroll
                for (int r = 0; r < 4; ++r) {
                    float x = fmaxf(acc[nt][r] + bb, 0.f);
                    Act[w * 16 + lq * 4 + r][nt * 16 + lm] = (short)f2bs(x);
                }
            }
        } else {
            float v[8][4];
#pragma unroll
            for (int nt = 0; nt < 8; ++nt) {
                float bb = b2f(bias[nt * 16 + lm]);
#pragma unroll
                for (int r = 0; r < 4; ++r) {
                    float x = acc[nt][r] + bb;
                    if (RELU_LAST) x = fmaxf(x, 0.f);
                    v[nt][r] = x;
                }
            }
            if constexpr (TRANS) {
                size_t grow = row0 + w * 16 + lq * 4;
                int bb2 = (int)(grow >> tshift);
                size_t rloc = grow & (((size_t)1 << tshift) - 1);
                bf16* YT = (bf16*)Y;
#pragma unroll
                for (int nt = 0; nt < 8; ++nt) {
                    int col = nt * 16 + lm;
                    ushort4 u;
                    u.x = f2bs(v[nt][0]); u.y = f2bs(v[nt][1]);
                    u.z = f2bs(v[nt][2]); u.w = f2bs(v[nt][3]);
                    *(ushort4*)(YT + ((size_t)bb2 * 128 + col) * (size_t)ldt + rloc) = u;
                }
            } else {
#pragma unroll
                for (int nt = 0; nt < 8; ++nt)
#pragma unroll
                    for (int r = 0; r < 4; ++r)
                        Y[(row0 + w * 16 + lq * 4 + r) * (size_t)ldy + nt * 16 + lm] =
                            Cvt<TOUT>::to(v[nt][r]);
            }
        }
    }
}

// ---------------------------------------------------------------------------
// FUSED tail: qenc (3 layers) -> q in Act; dec L0 (z|q), dec L1, final 128->3.
// ---------------------------------------------------------------------------
__global__ __launch_bounds__(256) void qdec_k(
    const bf16* __restrict__ xt32,
    const bf16* __restrict__ WtQ0, const bf16* __restrict__ qb0,
    const bf16* __restrict__ WtQ1, const bf16* __restrict__ qb1,
    const bf16* __restrict__ WtQ2, const bf16* __restrict__ qb2,
    const bf16* __restrict__ z,
    const bf16* __restrict__ WtDec0, const bf16* __restrict__ db0,
    const bf16* __restrict__ WtDec1, const bf16* __restrict__ db1,
    const bf16* __restrict__ W2, const bf16* __restrict__ b2v,
    const int* __restrict__ flag, void* __restrict__ out)
{
    __shared__ __align__(16) short Bs[8][64][8];
    __shared__ __align__(16) short Act[64][136];
    __shared__ bf16 w2s[384];
    int tid = threadIdx.x;
    int w = tid >> 6, l = tid & 63;
    int lm = l & 15, lq = l >> 4;
    size_t row0 = (size_t)blockIdx.x * 64;
    for (int t = tid; t < 384; t += 256) w2s[t] = W2[t];

    f32x4 acc[8];
#pragma unroll
    for (int i = 0; i < 8; i++) acc[i] = (f32x4){0.f, 0.f, 0.f, 0.f};

    // qenc L0 (K=32)
    {
        __syncthreads();
#pragma unroll
        for (int rr = 0; rr < 2; ++rr) {
            int idx = rr * 256 + tid;
            int nt = idx >> 6, ll = idx & 63;
            *(short8*)&Bs[nt][ll][0] =
                ld_frag(WtQ0 + (size_t)(nt * 16 + (ll & 15)) * 32 + (ll >> 4) * 8);
        }
        __syncthreads();
        short8 a = ld_frag(xt32 + (row0 + w * 16 + lm) * 32 + lq * 8);
#pragma unroll
        for (int nt = 0; nt < 8; ++nt) {
            short8 b = *(const short8*)&Bs[nt][l][0];
            acc[nt] = __builtin_amdgcn_mfma_f32_16x16x32_bf16(a, b, acc[nt], 0, 0, 0);
        }
#pragma unroll
        for (int nt = 0; nt < 8; ++nt) {
            float bb = b2f(qb0[nt * 16 + lm]);
#pragma unroll
            for (int r = 0; r < 4; ++r)
                Act[w * 16 + lq * 4 + r][nt * 16 + lm] = (short)f2bs(fmaxf(acc[nt][r] + bb, 0.f));
        }
    }
    // qenc L1 (relu) and L2 (no relu) -> Act
    for (int L = 1; L < 3; ++L) {
        const bf16* Wt = (L == 1) ? WtQ1 : WtQ2;
        const bf16* bias = (L == 1) ? qb1 : qb2;
#pragma unroll
        for (int i = 0; i < 8; i++) acc[i] = (f32x4){0.f, 0.f, 0.f, 0.f};
        for (int s = 0; s < 4; ++s) {
            int k0 = s * 32;
            __syncthreads();
#pragma unroll
            for (int rr = 0; rr < 2; ++rr) {
                int idx = rr * 256 + tid;
                int nt = idx >> 6, ll = idx & 63;
                *(short8*)&Bs[nt][ll][0] =
                    ld_frag(Wt + (size_t)(nt * 16 + (ll & 15)) * 128 + k0 + (ll >> 4) * 8);
            }
            __syncthreads();
            short8 a = *(const short8*)&Act[w * 16 + lm][k0 + lq * 8];
#pragma unroll
            for (int nt = 0; nt < 8; ++nt) {
                short8 b = *(const short8*)&Bs[nt][l][0];
                acc[nt] = __builtin_amdgcn_mfma_f32_16x16x32_bf16(a, b, acc[nt], 0, 0, 0);
            }
        }
        __syncthreads();
#pragma unroll
        for (int nt = 0; nt < 8; ++nt) {
            float bb = b2f(bias[nt * 16 + lm]);
#pragma unroll
            for (int r = 0; r < 4; ++r) {
                float x = acc[nt][r] + bb;
                if (L == 1) x = fmaxf(x, 0.f);
                Act[w * 16 + lq * 4 + r][nt * 16 + lm] = (short)f2bs(x);
            }
        }
    }
    // dec L0: K=256 = z (global) | q (Act); relu -> Act
    {
#pragma unroll
        for (int i = 0; i < 8; i++) acc[i] = (f32x4){0.f, 0.f, 0.f, 0.f};
        for (int s = 0; s < 8; ++s) {
            int k0 = s * 32;
            __syncthreads();
#pragma unroll
            for (int rr = 0; rr < 2; ++rr) {
                int idx = rr * 256 + tid;
                int nt = idx >> 6, ll = idx & 63;
                *(short8*)&Bs[nt][ll][0] =
                    ld_frag(WtDec0 + (size_t)(nt * 16 + (ll & 15)) * 256 + k0 + (ll >> 4) * 8);
            }
            __syncthreads();
            short8 a;
            if (k0 < 128) a = ld_frag(z + (row0 + w * 16 + lm) * (size_t)128 + k0 + lq * 8);
            else          a = *(const short8*)&Act[w * 16 + lm][(k0 - 128) + lq * 8];
#pragma unroll
            for (int nt = 0; nt < 8; ++nt) {
                short8 b = *(const short8*)&Bs[nt][l][0];
                acc[nt] = __builtin_amdgcn_mfma_f32_16x16x32_bf16(a, b, acc[nt], 0, 0, 0);
            }
        }
        __syncthreads();
#pragma unroll
        for (int nt = 0; nt < 8; ++nt) {
            float bb = b2f(db0[nt * 16 + lm]);
#pragma unroll
            for (int r = 0; r < 4; ++r)
                Act[w * 16 + lq * 4 + r][nt * 16 + lm] = (short)f2bs(fmaxf(acc[nt][r] + bb, 0.f));
        }
    }
    // dec L1: K=128 from Act; relu -> Act
    {
#pragma unroll
        for (int i = 0; i < 8; i++) acc[i] = (f32x4){0.f, 0.f, 0.f, 0.f};
        for (int s = 0; s < 4; ++s) {
            int k0 = s * 32;
            __syncthreads();
#pragma unroll
            for (int rr = 0; rr < 2; ++rr) {
                int idx = rr * 256 + tid;
                int nt = idx >> 6, ll = idx & 63;
                *(short8*)&Bs[nt][ll][0] =
                    ld_frag(WtDec1 + (size_t)(nt * 16 + (ll & 15)) * 128 + k0 + (ll >> 4) * 8);
            }
            __syncthreads();
            short8 a = *(const short8*)&Act[w * 16 + lm][k0 + lq * 8];
#pragma unroll
            for (int nt = 0; nt < 8; ++nt) {
                short8 b = *(const short8*)&Bs[nt][l][0];
                acc[nt] = __builtin_amdgcn_mfma_f32_16x16x32_bf16(a, b, acc[nt], 0, 0, 0);
            }
        }
        __syncthreads();
#pragma unroll
        for (int nt = 0; nt < 8; ++nt) {
            float bb = b2f(db1[nt * 16 + lm]);
#pragma unroll
            for (int r = 0; r < 4; ++r)
                Act[w * 16 + lq * 4 + r][nt * 16 + lm] = (short)f2bs(fmaxf(acc[nt][r] + bb, 0.f));
        }
    }
    __syncthreads();
    // final 128 -> 3
    if (tid < 192) {
        int row = tid / 3, col = tid - (tid / 3) * 3;
        float a = b2f(b2v[col]);
        for (int k8 = 0; k8 < 16; ++k8) {
            short8 av = *(const short8*)&Act[row][k8 * 8];
#pragma unroll
            for (int j = 0; j < 8; ++j)
                a += bs2f(av[j]) * b2f(w2s[(k8 * 8 + j) * 3 + col]);
        }
        size_t o = (row0 + row) * 3 + col;
        if (*flag) ((float*)out)[o] = a;
        else       ((bf16*)out)[o] = __float2bfloat16(a);
    }
}

// ---------------------------------------------------------------------------
// fused softmax stats. v2: 4096 blocks x 4 quads (pos staged once per block).
// ---------------------------------------------------------------------------
__global__ __launch_bounds__(256) void stats2_k(const bf16* __restrict__ xcp,
                                                const bf16* __restrict__ xtp,
                                                const bf16* __restrict__ pos,
                                                float4* __restrict__ cstC4,
                                                float4* __restrict__ cstT4) {
    __shared__ float px[NNODE], py[NNODE];
    int tid = threadIdx.x;
    for (int t = tid; t < NNODE; t += 256) {
        px[t] = b2f(pos[2 * t]);
        py[t] = b2f(pos[2 * t + 1]);
    }
    __syncthreads();
    int w = tid >> 6, l = tid & 63;
#pragma unroll
    for (int it = 0; it < 4; ++it) {
        int qb = blockIdx.x + it * 4096;
        const bf16* xp = (qb < 8192) ? xcp : xtp;
        float4* st4 = (qb < 8192) ? cstC4 : cstT4;
        int pb = qb & 8191;
        int p = pb * 4 + w;
        float x = b2f(xp[2 * p]), y = b2f(xp[2 * p + 1]);
        float vals[16];
        float m = -3.4e38f;
#pragma unroll
        for (int k = 0; k < 16; k++) {
            int n = k * 64 + l;
            float dx = x - px[n], dy = y - py[n];
            float v = -(dx * dx + dy * dy);
            vals[k] = v;
            m = fmaxf(m, v);
        }
#pragma unroll
        for (int off = 32; off; off >>= 1) m = fmaxf(m, __shfl_xor(m, off));
        float s = 0.f;
#pragma unroll
        for (int k = 0; k < 16; k++) s += __expf(vals[k] - m);
#pragma unroll
        for (int off = 32; off; off >>= 1) s += __shfl_xor(s, off);
        if (l == 0) st4[p] = make_float4(x, y, m, 1.f / s);
    }
}

// ---------------------------------------------------------------------------
// lat partials via MFMA. v2: cooperative LDS staging of emb chunks (dedup 4x),
// XOR-swizzled tile; up = K-step within the shared 64-col chunk.
// ---------------------------------------------------------------------------
__global__ __launch_bounds__(512, 4) void lat_mfma_k(const bf16* __restrict__ embT,
                                                     const float2* __restrict__ posf2,
                                                     const float4* __restrict__ cstC4,
                                                     P8 parts) {
    int i = blockIdx.x;
    int b = i & 7, r = i >> 3;
    int cs = r >> 4, nt = r & 15;
    int n0 = nt * 64;
    __shared__ __align__(16) float4 csh[512];
    __shared__ __align__(16) union ShU {
        short stage[2][8192];        // 2 x [128 rows][64 cols] bf16, swizzled
        float4 red[4][8][64];
    } sh;
    int tid = threadIdx.x;
    int w = tid >> 6, l = tid & 63;
    int wl = w & 3, up = w >> 2;
    int lm = l & 15, lq = l >> 4;
    int node = n0 + wl * 16 + lm;
    float2 pn = posf2[node];
    const bf16* ebase = embT + (size_t)b * (128 * LDE) + cs * 512;
    const float4* cbase = cstC4 + b * NC + cs * 512;
    csh[tid] = cbase[tid];

    int h0 = tid >> 3;
    int cb0 = (tid & 7) << 4;
    const char* g0 = (const char*)ebase + (size_t)h0 * (LDE * 2) + cb0;
    const size_t gH = (size_t)64 * (LDE * 2);
    int o0 = h0 * 128 + (cb0 ^ ((h0 & 7) << 4));   // swizzled LDS byte offset
    char* lbuf0 = (char*)&sh.stage[0][0];
    char* lbuf1 = (char*)&sh.stage[1][0];

    {
        uint4 rA = *(const uint4*)(g0);
        uint4 rB = *(const uint4*)(g0 + gH);
        *(uint4*)(lbuf0 + o0) = rA;
        *(uint4*)(lbuf0 + o0 + 64 * 128) = rB;
    }
    __syncthreads();

    f32x4 acc[8];
#pragma unroll
    for (int q = 0; q < 8; q++) acc[q] = (f32x4){0.f, 0.f, 0.f, 0.f};

    union AF { short8 s; u16 u[8]; };
    int rb = up * 64 + lq * 16;

    for (int ci = 0; ci < 8; ++ci) {
        char* cur = (ci & 1) ? lbuf1 : lbuf0;
        char* nxt = (ci & 1) ? lbuf0 : lbuf1;
        uint4 rA, rB;
        if (ci < 7) {
            const char* gs = g0 + (ci + 1) * 128;
            rA = *(const uint4*)(gs);
            rB = *(const uint4*)(gs + gH);
        }
        AF cw;
        int cidx = ci * 64 + up * 32 + lq * 8;
#pragma unroll
        for (int j = 0; j < 8; ++j) {
            float4 cc = csh[cidx + j];
            float dx = cc.x - pn.x, dy = cc.y - pn.y;
            cw.u[j] = f2bs(__expf(-(dx * dx + dy * dy) - cc.z) * cc.w);
        }
#pragma unroll
        for (int t2 = 0; t2 < 8; ++t2) {
            int h = t2 * 16 + lm;
            short8 bfr = *(const short8*)(cur + h * 128 + (rb ^ ((h & 7) << 4)));
            acc[t2] = __builtin_amdgcn_mfma_f32_16x16x32_bf16(cw.s, bfr, acc[t2], 0, 0, 0);
        }
        if (ci < 7) {
            *(uint4*)(nxt + o0) = rA;
            *(uint4*)(nxt + o0 + 64 * 128) = rB;
        }
        __syncthreads();
    }

    if (up) {
#pragma unroll
        for (int t2 = 0; t2 < 8; ++t2)
            sh.red[wl][t2][l] = make_float4(acc[t2][0], acc[t2][1], acc[t2][2], acc[t2][3]);
    }
    __syncthreads();
    if (!up) {
        float* part = parts.p[cs] + (((size_t)(b * NNODE + n0 + wl * 16 + lq * 4)) << 7) + lm;
#pragma unroll
        for (int t2 = 0; t2 < 8; ++t2) {
            float4 o = sh.red[wl][t2][l];
#pragma unroll
            for (int r2 = 0; r2 < 4; ++r2)
                part[(r2 << 7) + t2 * 16] = acc[t2][r2] + ((const float*)&o)[r2];
        }
    }
}

// ---------------------------------------------------------------------------
// z via MFMA. v2: same cooperative LDS staging as lat_mfma_k.
// ---------------------------------------------------------------------------
__global__ __launch_bounds__(512, 4) void z_mfma_k(const bf16* __restrict__ latT,
                                                   const float2* __restrict__ posf2,
                                                   const float4* __restrict__ cstT4,
                                                   bf16* __restrict__ z) {
    int i = blockIdx.x;
    int b = i & 7, tt = i >> 3;
    int t0 = tt * 64;
    __shared__ __align__(8) float2 posh[1024];
    __shared__ __align__(16) union ShU {
        short stage[2][8192];
        float4 red[4][8][64];
    } sh;
    int tid = threadIdx.x;
    int w = tid >> 6, l = tid & 63;
    int wl = w & 3, up = w >> 2;
    int lm = l & 15, lq = l >> 4;
    int t = t0 + wl * 16 + lm;
    float4 qs = cstT4[b * NTT + t];
    const bf16* lbase = latT + (size_t)b * (128 * LDL);
    for (int k = tid; k < 1024; k += 512) posh[k] = posf2[k];

    int h0 = tid >> 3;
    int cb0 = (tid & 7) << 4;
    const char* g0 = (const char*)lbase + (size_t)h0 * (LDL * 2) + cb0;
    const size_t gH = (size_t)64 * (LDL * 2);
    int o0 = h0 * 128 + (cb0 ^ ((h0 & 7) << 4));
    char* lbuf0 = (char*)&sh.stage[0][0];
    char* lbuf1 = (char*)&sh.stage[1][0];

    {
        uint4 rA = *(const uint4*)(g0);
        uint4 rB = *(const uint4*)(g0 + gH);
        *(uint4*)(lbuf0 + o0) = rA;
        *(uint4*)(lbuf0 + o0 + 64 * 128) = rB;
    }
    __syncthreads();

    f32x4 acc[8];
#pragma unroll
    for (int q = 0; q < 8; q++) acc[q] = (f32x4){0.f, 0.f, 0.f, 0.f};

    union AF { short8 s; u16 u[8]; };
    int rb = up * 64 + lq * 16;

    for (int ci = 0; ci < 16; ++ci) {
        char* cur = (ci & 1) ? lbuf1 : lbuf0;
        char* nxt = (ci & 1) ? lbuf0 : lbuf1;
        uint4 rA, rB;
        if (ci < 15) {
            const char* gs = g0 + (ci + 1) * 128;
            rA = *(const uint4*)(gs);
            rB = *(const uint4*)(gs + gH);
        }
        AF cw;
        int cidx = ci * 64 + up * 32 + lq * 8;
#pragma unroll
        for (int j = 0; j < 8; ++j) {
            float2 pn = posh[cidx + j];
            float dx = qs.x - pn.x, dy = qs.y - pn.y;
            cw.u[j] = f2bs(__expf(-(dx * dx + dy * dy) - qs.z) * qs.w);
        }
#pragma unroll
        for (int t2 = 0; t2 < 8; ++t2) {
            int h = t2 * 16 + lm;
            short8 bfr = *(const short8*)(cur + h * 128 + (rb ^ ((h & 7) << 4)));
            acc[t2] = __builtin_amdgcn_mfma_f32_16x16x32_bf16(cw.s, bfr, acc[t2], 0, 0, 0);
        }
        if (ci < 15) {
            *(uint4*)(nxt + o0) = rA;
            *(uint4*)(nxt + o0 + 64 * 128) = rB;
        }
        __syncthreads();
    }

    if (up) {
#pragma unroll
        for (int t2 = 0; t2 < 8; ++t2)
            sh.red[wl][t2][l] = make_float4(acc[t2][0], acc[t2][1], acc[t2][2], acc[t2][3]);
    }
    __syncthreads();
    if (!up) {
        bf16* zp = z + (((size_t)(b * NTT + t0 + wl * 16 + lq * 4)) << 7) + lm;
#pragma unroll
        for (int t2 = 0; t2 < 8; ++t2) {
            float4 o = sh.red[wl][t2][l];
#pragma unroll
            for (int r2 = 0; r2 < 4; ++r2)
                zp[(r2 << 7) + t2 * 16] = __float2bfloat16(acc[t2][r2] + ((const float*)&o)[r2]);
        }
    }
}

// ---------------------------------------------------------------------------
// edge gather v3: closed-form per-edge LN (sender row stats precomputed);
// edge loop unrolled x4 — four interleaved single-level dot-reduce chains
// hide the 6-shuffle cross-lane latency.
// ---------------------------------------------------------------------------
__global__ __launch_bounds__(256) void edge_gather_k(const bf16* __restrict__ PQ,
                                                     const float2* __restrict__ vstat,
                                                     const int* __restrict__ rowptr,
                                                     const int* __restrict__ csr_send,
                                                     const bf16* __restrict__ mb,
                                                     const bf16* __restrict__ g1,
                                                     const bf16* __restrict__ b1,
                                                     bf16* __restrict__ inbox) {
    int tid = threadIdx.x;
    int w = tid >> 6, l = tid & 63;
    int gw = blockIdx.x * 4 + w;
    int b = gw >> 10, n = gw & 1023;
    const bf16* pqb = PQ + ((size_t)b << 18);
    const float2* vsb = vstat + b * NNODE;
    float u0 = b2f(pqb[(n << 8) + l]) + b2f(mb[l]);
    float u1 = b2f(pqb[(n << 8) + l + 64]) + b2f(mb[l + 64]);
    float g0 = b2f(g1[l]), g1v = b2f(g1[l + 64]);
    float bb0 = b2f(b1[l]), bb1 = b2f(b1[l + 64]);
    // receiver-side stats (once per node)
    float s1 = u0 + u1, s2 = u0 * u0 + u1 * u1;
#pragma unroll
    for (int off = 32; off; off >>= 1) {
        s1 += __shfl_xor(s1, off);
        s2 += __shfl_xor(s2, off);
    }
    float aN = s1 * (1.f / 128.f);
    float Su = s2;
    int beg = rowptr[n], end = rowptr[n + 1];
    float R = 0.f, M = 0.f, t0 = 0.f, t1 = 0.f;
    int i = beg;
    for (; i + 3 < end; i += 4) {
        int sA = csr_send[i], sB = csr_send[i + 1];
        int sC = csr_send[i + 2], sD = csr_send[i + 3];
        const bf16* qA = pqb + (sA << 8) + 128;
        const bf16* qB = pqb + (sB << 8) + 128;
        const bf16* qC = pqb + (sC << 8) + 128;
        const bf16* qD = pqb + (sD << 8) + 128;
        float vA0 = b2f(qA[l]), vA1 = b2f(qA[l + 64]);
        float vB0 = b2f(qB[l]), vB1 = b2f(qB[l + 64]);
        float vC0 = b2f(qC[l]), vC1 = b2f(qC[l + 64]);
        float vD0 = b2f(qD[l]), vD1 = b2f(qD[l + 64]);
        float dA = u0 * vA0 + u1 * vA1;
        float dB = u0 * vB0 + u1 * vB1;
        float dC = u0 * vC0 + u1 * vC1;
        float dD = u0 * vD0 + u1 * vD1;
#pragma unroll
        for (int off = 32; off; off >>= 1) {
            dA += __shfl_xor(dA, off);
            dB += __shfl_xor(dB, off);
            dC += __shfl_xor(dC, off);
            dD += __shfl_xor(dD, off);
        }
        float2 stA = vsb[sA], stB = vsb[sB], stC = vsb[sC], stD = vsb[sD];
        float muA = aN + stA.x;
        float rsA = rsqrtf((Su + stA.y + 2.f * dA) * (1.f / 128.f) - muA * muA + 1e-5f);
        float muB = aN + stB.x;
        float rsB = rsqrtf((Su + stB.y + 2.f * dB) * (1.f / 128.f) - muB * muB + 1e-5f);
        float muC = aN + stC.x;
        float rsC = rsqrtf((Su + stC.y + 2.f * dC) * (1.f / 128.f) - muC * muC + 1e-5f);
        float muD = aN + stD.x;
        float rsD = rsqrtf((Su + stD.y + 2.f * dD) * (1.f / 128.f) - muD * muD + 1e-5f);
        R += (rsA + rsB) + (rsC + rsD);
        M += (rsA * muA + rsB * muB) + (rsC * muC + rsD * muD);
        t0 += (rsA * vA0 + rsB * vB0) + (rsC * vC0 + rsD * vD0);
        t1 += (rsA * vA1 + rsB * vB1) + (rsC * vC1 + rsD * vD1);
    }
    for (; i < end; ++i) {
        int s = csr_send[i];
        const bf16* q = pqb + (s << 8) + 128;
        float v0 = b2f(q[l]), v1 = b2f(q[l + 64]);
        float d = u0 * v0 + u1 * v1;
#pragma unroll
        for (int off = 32; off; off >>= 1) d += __shfl_xor(d, off);
        float2 st = vsb[s];
        float mu = aN + st.x;
        float var = (Su + st.y + 2.f * d) * (1.f / 128.f) - mu * mu;
        float rs = rsqrtf(var + 1e-5f);
        R += rs;
        M += rs * mu;
        t0 += rs * v0;
        t1 += rs * v1;
    }
    float deg = (float)(end - beg);
    float a0 = g0 * (u0 * R + t0 - M) + deg * bb0;
    float a1 = g1v * (u1 * R + t1 - M) + deg * bb1;
    bf16* inb = inbox + ((size_t)b << 17) + (n << 7);
    inb[l] = __float2bfloat16(a0);
    inb[l + 64] = __float2bfloat16(a1);
}

// ---------------------------------------------------------------------------
extern "C" void kernel_launch(void* const* d_in, const int* in_sizes, int n_in,
                              void* d_out, int out_size, void* d_ws, size_t ws_size,
                              hipStream_t stream) {
    const int* senders = (const int*)d_in[30];
    const int* receivers = (const int*)d_in[31];

    char* base = (char*)d_ws;
    size_t off = 0;
    auto alloc = [&](size_t bytes) { char* p = base + off; off += (bytes + 255) & ~(size_t)255; return p; };

    int* flag = (int*)alloc(256);

    Tab tab;
    int pref = 0;
    for (int i = 0; i < 30; ++i) { tab.src[i] = d_in[i]; tab.pref[i] = pref; pref += in_sizes[i]; }
    tab.pref[30] = pref;
    bf16* arena = (bf16*)alloc((size_t)pref * 2);
    auto C = [&](int i) { return arena + tab.pref[i]; };

    float4* cstC4 = (float4*)alloc(32768 * sizeof(float4));
    float4* cstT4 = (float4*)alloc(32768 * sizeof(float4));
    float* lat0  = (float*)alloc(8192 * 128 * 4);
    float* lat1  = (float*)alloc(8192 * 128 * 4);
    float* inboxf = (float*)alloc(8192 * 128 * 4);          // lat partials only
    bf16* inbox  = (bf16*)alloc(8192 * 128 * 2);            // bf16 inbox
    bf16* T1     = (bf16*)alloc((size_t)32768 * 128 * 2);
    bf16* T2     = (bf16*)alloc((size_t)32768 * 128 * 2);
    bf16* T3     = (bf16*)alloc((size_t)32768 * 128 * 2);
    bf16* embT   = (bf16*)alloc((size_t)8 * 128 * LDE * 2);
    bf16* latT   = (bf16*)alloc((size_t)8 * 128 * LDL * 2);
    bf16* xin32  = (bf16*)alloc((size_t)32768 * 32 * 2);
    bf16* xt32   = (bf16*)alloc((size_t)32768 * 32 * 2);
    float2* posf2 = (float2*)alloc(1024 * sizeof(float2));
    float2* vstat = (float2*)alloc(8192 * sizeof(float2));
    int* rowptr  = (int*)alloc(1025 * 4);
    int* csr_send = (int*)alloc(NEDGE * 4);
    bf16* WtEnc0 = (bf16*)alloc(128 * 32 * 2);
    bf16* WtQ0   = (bf16*)alloc(128 * 32 * 2);
    bf16* WtEnc1 = (bf16*)alloc(16384 * 2);
    bf16* WtEnc2 = (bf16*)alloc(16384 * 2);
    bf16* WtQ1   = (bf16*)alloc(16384 * 2);
    bf16* WtQ2   = (bf16*)alloc(16384 * 2);
    bf16* WtDec0 = (bf16*)alloc(32768 * 2);
    bf16* WtDec1 = (bf16*)alloc(16384 * 2);
    bf16* WtMsg  = (bf16*)alloc(32768 * 2);
    bf16* WtNode = (bf16*)alloc(32768 * 2);
    bf16* PQ     = T3;   // overlay: bf16 PQ (4 MB) in T3's region; disjoint lifetime
    (void)ws_size; (void)n_in; (void)out_size;

    detect_k<<<1, 256, 0, stream>>>((const u16*)d_in[3], flag);
    ingest_k<<<(pref + 255) / 256, 256, 0, stream>>>(tab, flag, arena);

    const bf16 *xc = C(0), *yc = C(1), *xt = C(2), *pos = C(3);
    const bf16 *enc_W0 = C(4), *enc_b0 = C(5), *enc_W1 = C(6), *enc_b1 = C(7), *enc_W2 = C(8), *enc_b2 = C(9);
    const bf16 *qenc_W0 = C(10), *qenc_b0 = C(11), *qenc_W1 = C(12), *qenc_b1 = C(13), *qenc_W2 = C(14), *qenc_b2 = C(15);
    const bf16 *dec_W0 = C(16), *dec_b0 = C(17), *dec_W1 = C(18), *dec_b1 = C(19), *dec_W2 = C(20), *dec_b2 = C(21);
    const bf16 *msg_W = C(22), *msg_b = C(23), *ln1_g = C(24), *ln1_b = C(25);
    const bf16 *node_W = C(26), *node_b = C(27), *ln2_g = C(28), *ln2_b = C(29);

    TT tt;
    const bf16* s11[11] = { enc_W1, enc_W2, qenc_W1, qenc_W2, dec_W1, dec_W0, msg_W, msg_W + 16384, node_W, enc_W0, qenc_W0 };
    bf16* d11[11]       = { WtEnc1, WtEnc2, WtQ1,    WtQ2,    WtDec1, WtDec0, WtMsg, WtMsg + 16384, WtNode, WtEnc0, WtQ0   };
    int sk11[11] = { 128, 128, 128, 128, 128, 256, 128, 128, 256, 5, 2 };
    int dk11[11] = { 128, 128, 128, 128, 128, 256, 128, 128, 256, 32, 32 };
    int tp = 0;
    for (int i = 0; i < 11; ++i) {
        tt.src[i] = s11[i]; tt.dst[i] = d11[i]; tt.srcK[i] = sk11[i]; tt.dK[i] = dk11[i];
        tt.pref[i] = tp; tp += dk11[i] * 128;
    }
    tt.pref[11] = tp;

    prep_trans_k<<<128 + (tp + 255) / 256, 256, 0, stream>>>(tt, xc, yc, xt, pos, xin32, xt32, posf2);
    build_csr_k<<<1, 1024, 0, stream>>>(receivers, senders, rowptr, csr_send);

    // encoder (fused 3-layer MLP): xin32 -> embT (transposed, padded rows)
    mlp_k<1, 3, 0, 1, bf16, bf16><<<512, 256, 0, stream>>>(
        xin32, nullptr, 32, WtEnc0, enc_b0, WtEnc1, enc_b1, WtEnc2, enc_b2, embT, 128, 12, LDE);

    stats2_k<<<4096, 256, 0, stream>>>(xc, xt, pos, cstC4, cstT4);

    P8 parts;
    parts.p[0] = lat1;
    parts.p[1] = inboxf;
    parts.p[2] = (float*)T1;
    parts.p[3] = (float*)T1 + 1048576;
    parts.p[4] = (float*)T2;
    parts.p[5] = (float*)T2 + 1048576;
    parts.p[6] = (float*)T3;
    parts.p[7] = (float*)T3 + 1048576;
    lat_mfma_k<<<1024, 512, 0, stream>>>(embT, posf2, cstC4, parts);

    // FUSED reduce8 + msg0: partials -> lat0 + PQ + vstat (one launch, was two)
    red_msg_k<<<256, 256, 0, stream>>>(parts, lat0, WtMsg, PQ, vstat);
    edge_gather_k<<<2048, 256, 0, stream>>>(PQ, vstat, rowptr, csr_send, msg_b, ln1_g, ln1_b, inbox);
    node_msg_k<<<256, 256, 0, stream>>>(lat0, inbox, WtNode, node_b, ln2_g, ln2_b, WtMsg, lat1, PQ, vstat);
    edge_gather_k<<<2048, 256, 0, stream>>>(PQ, vstat, rowptr, csr_send, msg_b, ln1_g, ln1_b, inbox);
    node_msg_k<<<256, 256, 0, stream>>>(lat1, inbox, WtNode, node_b, ln2_g, ln2_b, WtMsg, lat0, PQ, vstat);
    edge_gather_k<<<2048, 256, 0, stream>>>(PQ, vstat, rowptr, csr_send, msg_b, ln1_g, ln1_b, inbox);
    node_msg_k<<<256, 256, 0, stream>>>(lat0, inbox, WtNode, node_b, ln2_g, ln2_b, WtMsg, lat1, PQ, vstat);
    edge_gather_k<<<2048, 256, 0, stream>>>(PQ, vstat, rowptr, csr_send, msg_b, ln1_g, ln1_b, inbox);
    mfma_gemm_k<8, 1, 0, 1, 1, float, bf16, bf16><<<128, 256, 0, stream>>>(lat1, inbox, 128, WtNode, node_b, ln2_g, ln2_b, latT, 128, 10, LDL, nullptr);

    // z -> T2 (bf16)
    z_mfma_k<<<512, 512, 0, stream>>>(latT, posf2, cstT4, T2);

    // fused tail: qenc(xt32) + dec(z|q) + final -> out
    qdec_k<<<512, 256, 0, stream>>>(xt32,
                                    WtQ0, qenc_b0, WtQ1, qenc_b1, WtQ2, qenc_b2,
                                    T2,
                                    WtDec0, dec_b0, WtDec1, dec_b1,
                                    dec_W2, dec_b2, flag, d_out);
}